// Round 5
// baseline (130.096 us; speedup 1.0000x reference)
//
#include <hip/hip_runtime.h>
#include <hip/hip_bf16.h>
#include <math.h>

#define NROWS 4096
#define DIM   256
#define HALF_MASK 2047
#define BLOCK 256

typedef __attribute__((ext_vector_type(8))) short bf16x8;
typedef __attribute__((ext_vector_type(4))) float f32x4;

// order-preserving float -> uint transform (ascending uint == ascending float)
__device__ __forceinline__ unsigned fkey(float f) {
    unsigned u = __float_as_uint(f);
    return (u & 0x80000000u) ? ~u : (u | 0x80000000u);
}
// inverse of fkey
__device__ __forceinline__ float unfkey(unsigned u) {
    unsigned b = (u & 0x80000000u) ? (u & 0x7fffffffu) : ~u;
    return __uint_as_float(b);
}

// ===========================================================================
// FAST PATH: prep -> bf16 MFMA Gram -> wave-autonomous per-row select
// ===========================================================================

__global__ void prep_bf16_kernel(const float* __restrict__ feat,
                                 const int* __restrict__ labels,
                                 short* __restrict__ fnb,
                                 float* __restrict__ sq,
                                 unsigned char* __restrict__ lab8,
                                 float* __restrict__ out)
{
    const int row  = blockIdx.x * 4 + (threadIdx.x >> 6);
    const int lane = threadIdx.x & 63;
    float4 x = ((const float4*)feat)[(size_t)row * 64 + lane];
    float ss = x.x*x.x + x.y*x.y + x.z*x.z + x.w*x.w;
    #pragma unroll
    for (int m = 1; m < 64; m <<= 1) ss += __shfl_xor(ss, m, 64);
    const float nrm = sqrtf(ss);
    float4 f; f.x = x.x/nrm; f.y = x.y/nrm; f.z = x.z/nrm; f.w = x.w/nrm;

    union { __hip_bfloat16 b; unsigned short s; } cv[4];
    cv[0].b = __float2bfloat16(f.x); cv[1].b = __float2bfloat16(f.y);
    cv[2].b = __float2bfloat16(f.z); cv[3].b = __float2bfloat16(f.w);
    ushort4 h; h.x = cv[0].s; h.y = cv[1].s; h.z = cv[2].s; h.w = cv[3].s;
    ((ushort4*)fnb)[(size_t)row * 64 + lane] = h;

    float s2 = f.x*f.x + f.y*f.y + f.z*f.z + f.w*f.w;
    #pragma unroll
    for (int m = 1; m < 64; m <<= 1) s2 += __shfl_xor(s2, m, 64);
    if (lane == 0) {
        sq[row]   = s2;
        lab8[row] = (unsigned char)labels[row & HALF_MASK];
    }
    if (blockIdx.x == 0 && threadIdx.x == 0) out[0] = 0.0f;
}

// Gram: S = fn * fn^T (4096x4096, K=256), bf16 MFMA 16x16x32, fp32 out.
__global__ __launch_bounds__(256) void gram_kernel(
        const short* __restrict__ fnb, float* __restrict__ S)
{
    __shared__ __align__(16) short As[128 * 64];
    __shared__ __align__(16) short Bs[128 * 64];

    const int tid  = threadIdx.x;
    const int lane = tid & 63;
    const int wv   = tid >> 6;
    const int wm   = wv >> 1, wn = wv & 1;
    const int bi   = blockIdx.x >> 5;
    const int bj   = blockIdx.x & 31;
    const int i0   = bi * 128, j0 = bj * 128;

    f32x4 acc[4][4];
    const f32x4 zero = {0.f, 0.f, 0.f, 0.f};
    #pragma unroll
    for (int a = 0; a < 4; ++a)
        #pragma unroll
        for (int b = 0; b < 4; ++b) acc[a][b] = zero;

    const int srow   = tid >> 3;
    const int schunk = tid & 7;

    for (int kt = 0; kt < 4; ++kt) {
        #pragma unroll
        for (int is = 0; is < 4; ++is) {
            const int row = is * 32 + srow;
            const size_t gsrc = (size_t)kt * 64 + schunk * 8;
            uint4 va = *(const uint4*)(fnb + (size_t)(i0 + row) * DIM + gsrc);
            uint4 vb = *(const uint4*)(fnb + (size_t)(j0 + row) * DIM + gsrc);
            const int dst = row * 64 + ((schunk ^ (row & 7)) * 8);
            *(uint4*)(As + dst) = va;
            *(uint4*)(Bs + dst) = vb;
        }
        __syncthreads();
        #pragma unroll
        for (int kk = 0; kk < 2; ++kk) {
            bf16x8 af[4], bfr[4];
            #pragma unroll
            for (int mi = 0; mi < 4; ++mi) {
                const int row = wm * 64 + mi * 16 + (lane & 15);
                const int ch  = kk * 4 + (lane >> 4);
                af[mi] = *(const bf16x8*)(As + row * 64 + ((ch ^ (row & 7)) * 8));
            }
            #pragma unroll
            for (int ni = 0; ni < 4; ++ni) {
                const int row = wn * 64 + ni * 16 + (lane & 15);
                const int ch  = kk * 4 + (lane >> 4);
                bfr[ni] = *(const bf16x8*)(Bs + row * 64 + ((ch ^ (row & 7)) * 8));
            }
            #pragma unroll
            for (int mi = 0; mi < 4; ++mi)
                #pragma unroll
                for (int ni = 0; ni < 4; ++ni)
                    acc[mi][ni] = __builtin_amdgcn_mfma_f32_16x16x32_bf16(
                        af[mi], bfr[ni], acc[mi][ni], 0, 0, 0);
        }
        __syncthreads();
    }

    const int cq = lane >> 4;
    const int cc = lane & 15;
    #pragma unroll
    for (int mi = 0; mi < 4; ++mi) {
        #pragma unroll
        for (int ni = 0; ni < 4; ++ni) {
            const int col  = j0 + wn * 64 + ni * 16 + cc;
            const int rowb = i0 + wm * 64 + mi * 16 + cq * 4;
            #pragma unroll
            for (int v = 0; v < 4; ++v)
                S[(size_t)(rowb + v) * NROWS + col] = acc[mi][ni][v];
        }
    }
}

// pass-0 dense histogram add: 1/2-digit wave-uniform leader path, else per-lane
__device__ __forceinline__ void hist_add_dense(unsigned* h, unsigned dg, int lane) {
    const unsigned d0 = (unsigned)__builtin_amdgcn_readfirstlane((int)dg);
    const unsigned long long m0 = __ballot(dg == d0);
    if (m0 == ~0ull) {
        if (lane == 0) atomicAdd(&h[d0], 64u);
    } else {
        const int l1 = __ffsll((long long)(~m0)) - 1;
        const unsigned d1 = (unsigned)__builtin_amdgcn_readlane((int)dg, l1);
        const unsigned long long m1 = __ballot(dg == d1);
        if ((m0 | m1) == ~0ull) {
            if (lane == 0)       atomicAdd(&h[d0], (unsigned)__popcll(m0));
            else if (lane == l1) atomicAdd(&h[d1], (unsigned)__popcll(m1));
        } else {
            atomicAdd(&h[dg], 1u);
        }
    }
}

// wave-autonomous per-row kernel: one wave per row, ZERO block barriers.
// Keys for the wave's 64 columns/lane live in registers (all static indices);
// per-wave private 256-bin histogram in LDS (DS ops of one wave are in-order).
__global__ __launch_bounds__(256, 4) void rowsel_wave_kernel(
        const float* __restrict__ S,
        const float* __restrict__ sq,
        const unsigned char* __restrict__ lab8,
        float* __restrict__ out)
{
    __shared__ unsigned hist[4][256];

    const int tid  = threadIdx.x;
    const int lane = tid & 63;
    const int w    = tid >> 6;
    const int row  = blockIdx.x * 4 + w;

    const float4*   S4 = (const float4*)(S + (size_t)row * NROWS);
    const float4*   Q4 = (const float4*)sq;
    const unsigned* L4 = (const unsigned*)lab8;
    unsigned* hw = &hist[w][0];

    // zero my wave's histogram (wave-private)
    ((uint4*)hw)[lane] = make_uint4(0u, 0u, 0u, 0u);

    // ---- load row, build keys (registers), Z, fused pass-0 histogram ----
    unsigned u[16][4];
    float z = 0.f;
    #pragma unroll
    for (int c = 0; c < 16; ++c) {
        const float4 v = S4[c * 64 + lane];
        const float4 q = Q4[c * 64 + lane];
        const int jb = c * 256 + lane * 4;
        u[c][0] = fkey(fmaf(-2.f, v.x, q.x));
        u[c][1] = fkey(fmaf(-2.f, v.y, q.y));
        u[c][2] = fkey(fmaf(-2.f, v.z, q.z));
        u[c][3] = fkey(fmaf(-2.f, v.w, q.w));
        z += (jb + 0 == row) ? 0.f : __expf(10.f * v.x);
        z += (jb + 1 == row) ? 0.f : __expf(10.f * v.y);
        z += (jb + 2 == row) ? 0.f : __expf(10.f * v.z);
        z += (jb + 3 == row) ? 0.f : __expf(10.f * v.w);
        hist_add_dense(hw, u[c][0] >> 24, lane);
        hist_add_dense(hw, u[c][1] >> 24, lane);
        hist_add_dense(hw, u[c][2] >> 24, lane);
        hist_add_dense(hw, u[c][3] >> 24, lane);
    }
    #pragma unroll
    for (int m = 1; m < 64; m <<= 1) z += __shfl_xor(z, m, 64);

    // ---- 4 radix passes: wave-local suffix scan, select threshold digit ----
    unsigned P = 0u, K = 128u;
    #pragma unroll
    for (int pass = 0; pass < 4; ++pass) {
        const int shift = 24 - 8 * pass;
        if (pass > 0) {
            ((uint4*)hw)[lane] = make_uint4(0u, 0u, 0u, 0u);
            #pragma unroll
            for (int c = 0; c < 16; ++c)
                #pragma unroll
                for (int e = 0; e < 4; ++e) {
                    const unsigned uu = u[c][e];
                    if (((uu ^ P) >> (shift + 8)) == 0u)
                        atomicAdd(&hw[(uu >> shift) & 255u], 1u);
                }
        }
        // read my 4 bins, lane-local + wave suffix scan
        const uint4 h = ((const uint4*)hw)[lane];
        const unsigned s3 = h.w;
        const unsigned s2 = h.z + s3;
        const unsigned s1 = h.y + s2;
        const unsigned s0 = h.x + s1;                 // lane total
        unsigned x = s0;
        #pragma unroll
        for (int d = 1; d < 64; d <<= 1) {
            const unsigned y = __shfl_down(x, d, 64);
            if (lane + d < 64) x += y;
        }
        const unsigned E = x - s0;                    // sum over lanes > lane
        unsigned pk = 0u;
        {
            const unsigned Sv0 = E + s0, Sv1 = E + s1, Sv2 = E + s2, Sv3 = E + s3;
            if (Sv0 >= K && Sv0 - h.x < K) pk = ((unsigned)(lane*4+0) << 16) | (K - (Sv0 - h.x));
            if (Sv1 >= K && Sv1 - h.y < K) pk = ((unsigned)(lane*4+1) << 16) | (K - (Sv1 - h.y));
            if (Sv2 >= K && Sv2 - h.z < K) pk = ((unsigned)(lane*4+2) << 16) | (K - (Sv2 - h.z));
            if (Sv3 >= K && Sv3 - h.w < K) pk = ((unsigned)(lane*4+3) << 16) | (K - (Sv3 - h.w));
        }
        #pragma unroll
        for (int m = 1; m < 64; m <<= 1) pk |= __shfl_xor(pk, m, 64);
        P |= (pk >> 16) << shift;
        K  = pk & 0xFFFFu;
    }

    // ---- tie ranks (lane-major order) ----
    int tcnt = 0;
    #pragma unroll
    for (int c = 0; c < 16; ++c)
        #pragma unroll
        for (int e = 0; e < 4; ++e) tcnt += (u[c][e] == P) ? 1 : 0;
    int p = tcnt;
    #pragma unroll
    for (int d = 1; d < 64; d <<= 1) {
        const int o = __shfl_up(p, d, 64);
        if (lane >= d) p += o;
    }
    int t = p - tcnt;                                 // exclusive prefix

    // ---- accumulate over selected & same-class & j != row ----
    const unsigned my = lab8[row];
    float sd = 0.f; int cnt = 0;
    #pragma unroll
    for (int c = 0; c < 16; ++c) {
        const float4 q = Q4[c * 64 + lane];
        float qa[4]; *(float4*)qa = q;
        const unsigned lw = L4[c * 64 + lane];
        const int jb = c * 256 + lane * 4;
        #pragma unroll
        for (int e = 0; e < 4; ++e) {
            const unsigned uu = u[c][e];
            bool sel = (uu > P);
            if (uu == P) { sel = (t < (int)K); ++t; }
            if (sel && (jb + e != row) && (((lw >> (8 * e)) & 255u) == my)) {
                ++cnt;
                sd += 0.5f * (qa[e] - unfkey(uu));
            }
        }
    }
    #pragma unroll
    for (int m = 1; m < 64; m <<= 1) {
        sd  += __shfl_xor(sd, m, 64);
        cnt += __shfl_xor(cnt, m, 64);
    }
    if (lane == 0 && cnt > 0) {
        const float mlpp = (10.f * sd) / (float)cnt - __logf(z);
        atomicAdd(out, -(0.1f / 0.07f) * mlpp * (1.f / (float)NROWS));
    }
}

// ===========================================================================
// FALLBACK PATH (small d_ws): R2 fused kernels (verified correct)
// ===========================================================================

__global__ void prep_kernel(const float* __restrict__ feat,
                            const int* __restrict__ labels,
                            float* __restrict__ fn,
                            float* __restrict__ sq,
                            unsigned char* __restrict__ lab8,
                            float* __restrict__ out)
{
    const int row  = blockIdx.x * 4 + (threadIdx.x >> 6);
    const int lane = threadIdx.x & 63;
    float4 x = ((const float4*)feat)[(size_t)row * 64 + lane];
    float ss = x.x*x.x + x.y*x.y + x.z*x.z + x.w*x.w;
    #pragma unroll
    for (int m = 1; m < 64; m <<= 1) ss += __shfl_xor(ss, m, 64);
    const float nrm = sqrtf(ss);
    float4 f; f.x = x.x/nrm; f.y = x.y/nrm; f.z = x.z/nrm; f.w = x.w/nrm;
    ((float4*)fn)[(size_t)row * 64 + lane] = f;
    float s2 = f.x*f.x + f.y*f.y + f.z*f.z + f.w*f.w;
    #pragma unroll
    for (int m = 1; m < 64; m <<= 1) s2 += __shfl_xor(s2, m, 64);
    if (lane == 0) {
        sq[row]  = s2;
        lab8[row] = (unsigned char)labels[row & HALF_MASK];
    }
    if (blockIdx.x == 0 && threadIdx.x == 0) out[0] = 0.0f;
}

#define R 4
__global__ __launch_bounds__(BLOCK, 3) void rowloss_kernel(
        const float* __restrict__ fn,
        const float* __restrict__ sq,
        const unsigned char* __restrict__ lab8,
        float* __restrict__ out)
{
    __shared__ __align__(16) float fi[R][DIM];
    __shared__ unsigned hist[R * 256];
    __shared__ float    wz[R][4];
    __shared__ unsigned wsc[R][4];
    __shared__ unsigned selT[R], selK[R];
    __shared__ float    wsd[R][4];
    __shared__ int      wcnt[R][4];

    const int tid  = threadIdx.x;
    const int lane = tid & 63;
    const int wv   = tid >> 6;
    const int i0   = blockIdx.x * R;
    const int j0   = tid * 16;

    for (int idx = tid; idx < R * DIM; idx += BLOCK)
        fi[idx >> 8][idx & 255] = fn[(size_t)i0 * DIM + idx];
    __syncthreads();

    const float4* fn4 = (const float4*)fn;
    const float4* fi4 = (const float4*)&fi[0][0];

    float acc[16][R];
    #pragma unroll
    for (int jj = 0; jj < 16; ++jj)
        #pragma unroll
        for (int r = 0; r < R; ++r) acc[jj][r] = 0.0f;

    for (int c = 0; c < 32; ++c) {
        float fir[R][8];
        #pragma unroll
        for (int r = 0; r < R; ++r) {
            float4 a = fi4[r * 64 + c * 2];
            float4 b = fi4[r * 64 + c * 2 + 1];
            fir[r][0] = a.x; fir[r][1] = a.y; fir[r][2] = a.z; fir[r][3] = a.w;
            fir[r][4] = b.x; fir[r][5] = b.y; fir[r][6] = b.z; fir[r][7] = b.w;
        }
        #pragma unroll
        for (int jj = 0; jj < 16; ++jj) {
            const float4* pp = fn4 + (size_t)(j0 + jj) * 64 + c * 2;
            float4 x = pp[0];
            float4 y = pp[1];
            #pragma unroll
            for (int r = 0; r < R; ++r) {
                float s = acc[jj][r];
                s = fmaf(x.x, fir[r][0], s); s = fmaf(x.y, fir[r][1], s);
                s = fmaf(x.z, fir[r][2], s); s = fmaf(x.w, fir[r][3], s);
                s = fmaf(y.x, fir[r][4], s); s = fmaf(y.y, fir[r][5], s);
                s = fmaf(y.z, fir[r][6], s); s = fmaf(y.w, fir[r][7], s);
                acc[jj][r] = s;
            }
        }
    }

    float sqr[16];
    #pragma unroll
    for (int k = 0; k < 16; ++k) sqr[k] = sq[j0 + k];

    float lzr[R];
    {
        float zloc[R];
        #pragma unroll
        for (int r = 0; r < R; ++r) {
            const int ir = i0 + r;
            float z = 0.0f;
            #pragma unroll
            for (int k = 0; k < 16; ++k) {
                float e = __expf(10.0f * acc[k][r]);
                z += (j0 + k == ir) ? 0.0f : e;
            }
            zloc[r] = z;
        }
        #pragma unroll
        for (int r = 0; r < R; ++r) {
            float z = zloc[r];
            #pragma unroll
            for (int m = 1; m < 64; m <<= 1) z += __shfl_xor(z, m, 64);
            if (lane == 0) wz[r][wv] = z;
        }
        __syncthreads();
        #pragma unroll
        for (int r = 0; r < R; ++r)
            lzr[r] = __logf(wz[r][0] + wz[r][1] + wz[r][2] + wz[r][3]);
    }

    unsigned Pr[R] = {0, 0, 0, 0};
    unsigned Kr[R] = {128u, 128u, 128u, 128u};
    #pragma unroll
    for (int pass = 0; pass < 4; ++pass) {
        const int shift = 24 - 8 * pass;
        #pragma unroll
        for (int r = 0; r < R; ++r) hist[r * 256 + tid] = 0u;
        __syncthreads();
        #pragma unroll
        for (int r = 0; r < R; ++r) {
            #pragma unroll
            for (int k = 0; k < 16; ++k) {
                unsigned uu = fkey(fmaf(-2.0f, acc[k][r], sqr[k]));
                bool act = (pass == 0) ||
                    (((unsigned long long)(uu ^ Pr[r]) >> (shift + 8)) == 0ull);
                if (act) atomicAdd(&hist[r * 256 + ((uu >> shift) & 255u)], 1u);
            }
        }
        __syncthreads();
        unsigned g[R], Pv[R];
        #pragma unroll
        for (int r = 0; r < R; ++r) { g[r] = hist[r * 256 + (255 - tid)]; Pv[r] = g[r]; }
        #pragma unroll
        for (int dd = 1; dd < 64; dd <<= 1) {
            #pragma unroll
            for (int r = 0; r < R; ++r) {
                unsigned o = __shfl_up(Pv[r], dd, 64);
                if (lane >= dd) Pv[r] += o;
            }
        }
        if (lane == 63) {
            #pragma unroll
            for (int r = 0; r < R; ++r) wsc[r][wv] = Pv[r];
        }
        __syncthreads();
        #pragma unroll
        for (int r = 0; r < R; ++r) {
            unsigned off = 0;
            #pragma unroll
            for (int ww = 0; ww < 4; ++ww) if (ww < wv) off += wsc[r][ww];
            const unsigned Sv = Pv[r] + off;
            const unsigned Sn = Sv - g[r];
            if (Sv >= Kr[r] && Sn < Kr[r]) {
                selT[r] = Pr[r] | ((unsigned)(255 - tid) << shift);
                selK[r] = Kr[r] - Sn;
            }
        }
        __syncthreads();
        #pragma unroll
        for (int r = 0; r < R; ++r) { Pr[r] = selT[r]; Kr[r] = selK[r]; }
        __syncthreads();
    }

    int tb[R];
    {
        int tcr[R], Pt[R];
        #pragma unroll
        for (int r = 0; r < R; ++r) {
            int c = 0;
            #pragma unroll
            for (int k = 0; k < 16; ++k)
                if (fkey(fmaf(-2.0f, acc[k][r], sqr[k])) == Pr[r]) c++;
            tcr[r] = c; Pt[r] = c;
        }
        #pragma unroll
        for (int dd = 1; dd < 64; dd <<= 1) {
            #pragma unroll
            for (int r = 0; r < R; ++r) {
                int o = __shfl_up(Pt[r], dd, 64);
                if (lane >= dd) Pt[r] += o;
            }
        }
        if (lane == 63) {
            #pragma unroll
            for (int r = 0; r < R; ++r) wsc[r][wv] = (unsigned)Pt[r];
        }
        __syncthreads();
        #pragma unroll
        for (int r = 0; r < R; ++r) {
            int off = 0;
            #pragma unroll
            for (int ww = 0; ww < 4; ++ww) if (ww < wv) off += (int)wsc[r][ww];
            tb[r] = Pt[r] + off - tcr[r];
        }
    }

    const uint4 labv = ((const uint4*)lab8)[tid];
    const unsigned labw[4] = {labv.x, labv.y, labv.z, labv.w};

    #pragma unroll
    for (int r = 0; r < R; ++r) {
        const int ir = i0 + r;
        const unsigned my = lab8[ir];
        float sd = 0.0f; int cnt = 0; int t = tb[r];
        #pragma unroll
        for (int k = 0; k < 16; ++k) {
            const unsigned uu = fkey(fmaf(-2.0f, acc[k][r], sqr[k]));
            bool sel = (uu > Pr[r]);
            if (uu == Pr[r]) { sel = (t < (int)Kr[r]); t++; }
            const unsigned lj = (labw[k >> 2] >> ((k & 3) * 8)) & 255u;
            if (sel && (j0 + k != ir) && lj == my) { cnt++; sd += acc[k][r]; }
        }
        #pragma unroll
        for (int m = 1; m < 64; m <<= 1) {
            sd  += __shfl_xor(sd, m, 64);
            cnt += __shfl_xor(cnt, m, 64);
        }
        if (lane == 0) { wsd[r][wv] = sd; wcnt[r][wv] = cnt; }
    }
    __syncthreads();

    if (tid < R) {
        const int r = tid;
        const int c = wcnt[r][0] + wcnt[r][1] + wcnt[r][2] + wcnt[r][3];
        if (c > 0) {
            const float sd = wsd[r][0] + wsd[r][1] + wsd[r][2] + wsd[r][3];
            const float mlpp = (10.0f * sd) / (float)c - lzr[r];
            atomicAdd(out, -(0.1f / 0.07f) * mlpp * (1.0f / (float)NROWS));
        }
    }
}

// ===========================================================================

extern "C" void kernel_launch(void* const* d_in, const int* in_sizes, int n_in,
                              void* d_out, int out_size, void* d_ws, size_t ws_size,
                              hipStream_t stream) {
    (void)in_sizes; (void)n_in; (void)out_size;
    const float* feat  = (const float*)d_in[0];
    const int* labels  = (const int*)d_in[1];
    float* out = (float*)d_out;

    const size_t offS = 0;                                   // 4096*4096 f32
    const size_t offF = (size_t)NROWS * NROWS * 4;           // fn bf16
    const size_t offQ = offF + (size_t)NROWS * DIM * 2;      // sq f32
    const size_t offL = offQ + (size_t)NROWS * 4;            // labels u8
    const size_t need = offL + (size_t)NROWS;

    if (ws_size >= need) {
        float* S   = (float*)((char*)d_ws + offS);
        short* fnb = (short*)((char*)d_ws + offF);
        float* sq  = (float*)((char*)d_ws + offQ);
        unsigned char* lab8 = (unsigned char*)((char*)d_ws + offL);

        prep_bf16_kernel<<<NROWS / 4, BLOCK, 0, stream>>>(feat, labels, fnb, sq, lab8, out);
        gram_kernel<<<(NROWS / 128) * (NROWS / 128), BLOCK, 0, stream>>>(fnb, S);
        rowsel_wave_kernel<<<NROWS / 4, BLOCK, 0, stream>>>(S, sq, lab8, out);
    } else {
        float* fn = (float*)d_ws;
        float* sq = fn + (size_t)NROWS * DIM;
        unsigned char* lab8 = (unsigned char*)(sq + NROWS);

        prep_kernel<<<NROWS / 4, BLOCK, 0, stream>>>(feat, labels, fn, sq, lab8, out);
        rowloss_kernel<<<NROWS / R, BLOCK, 0, stream>>>(fn, sq, lab8, out);
    }
}

// Round 6
// 114.112 us; speedup vs baseline: 1.1401x; 1.1401x over previous
//
#include <hip/hip_runtime.h>
#include <hip/hip_bf16.h>
#include <math.h>

#define NROWS 4096
#define DIM   256
#define HALF_MASK 2047
#define BLOCK 256

typedef __attribute__((ext_vector_type(8))) short bf16x8;
typedef __attribute__((ext_vector_type(4))) float f32x4;

// order-preserving float -> uint transform (ascending uint == ascending float)
__device__ __forceinline__ unsigned fkey(float f) {
    unsigned u = __float_as_uint(f);
    return (u & 0x80000000u) ? ~u : (u | 0x80000000u);
}
// inverse of fkey
__device__ __forceinline__ float unfkey(unsigned u) {
    unsigned b = (u & 0x80000000u) ? (u & 0x7fffffffu) : ~u;
    return __uint_as_float(b);
}

// ===========================================================================
// FAST PATH: prep -> bf16 MFMA Gram -> wave-autonomous per-row select
// ===========================================================================

__global__ void prep_bf16_kernel(const float* __restrict__ feat,
                                 const int* __restrict__ labels,
                                 short* __restrict__ fnb,
                                 float* __restrict__ sq,
                                 unsigned char* __restrict__ lab8,
                                 float* __restrict__ out)
{
    const int row  = blockIdx.x * 4 + (threadIdx.x >> 6);
    const int lane = threadIdx.x & 63;
    float4 x = ((const float4*)feat)[(size_t)row * 64 + lane];
    float ss = x.x*x.x + x.y*x.y + x.z*x.z + x.w*x.w;
    #pragma unroll
    for (int m = 1; m < 64; m <<= 1) ss += __shfl_xor(ss, m, 64);
    const float nrm = sqrtf(ss);
    float4 f; f.x = x.x/nrm; f.y = x.y/nrm; f.z = x.z/nrm; f.w = x.w/nrm;

    union { __hip_bfloat16 b; unsigned short s; } cv[4];
    cv[0].b = __float2bfloat16(f.x); cv[1].b = __float2bfloat16(f.y);
    cv[2].b = __float2bfloat16(f.z); cv[3].b = __float2bfloat16(f.w);
    ushort4 h; h.x = cv[0].s; h.y = cv[1].s; h.z = cv[2].s; h.w = cv[3].s;
    ((ushort4*)fnb)[(size_t)row * 64 + lane] = h;

    float s2 = f.x*f.x + f.y*f.y + f.z*f.z + f.w*f.w;
    #pragma unroll
    for (int m = 1; m < 64; m <<= 1) s2 += __shfl_xor(s2, m, 64);
    if (lane == 0) {
        sq[row]   = s2;
        lab8[row] = (unsigned char)labels[row & HALF_MASK];
    }
    if (blockIdx.x == 0 && threadIdx.x == 0) out[0] = 0.0f;
}

// Gram: S = fn * fn^T (4096x4096, K=256), bf16 MFMA 16x16x32, fp32 out.
__global__ __launch_bounds__(256) void gram_kernel(
        const short* __restrict__ fnb, float* __restrict__ S)
{
    __shared__ __align__(16) short As[128 * 64];
    __shared__ __align__(16) short Bs[128 * 64];

    const int tid  = threadIdx.x;
    const int lane = tid & 63;
    const int wv   = tid >> 6;
    const int wm   = wv >> 1, wn = wv & 1;
    const int bi   = blockIdx.x >> 5;
    const int bj   = blockIdx.x & 31;
    const int i0   = bi * 128, j0 = bj * 128;

    f32x4 acc[4][4];
    const f32x4 zero = {0.f, 0.f, 0.f, 0.f};
    #pragma unroll
    for (int a = 0; a < 4; ++a)
        #pragma unroll
        for (int b = 0; b < 4; ++b) acc[a][b] = zero;

    const int srow   = tid >> 3;
    const int schunk = tid & 7;

    for (int kt = 0; kt < 4; ++kt) {
        #pragma unroll
        for (int is = 0; is < 4; ++is) {
            const int row = is * 32 + srow;
            const size_t gsrc = (size_t)kt * 64 + schunk * 8;
            uint4 va = *(const uint4*)(fnb + (size_t)(i0 + row) * DIM + gsrc);
            uint4 vb = *(const uint4*)(fnb + (size_t)(j0 + row) * DIM + gsrc);
            const int dst = row * 64 + ((schunk ^ (row & 7)) * 8);
            *(uint4*)(As + dst) = va;
            *(uint4*)(Bs + dst) = vb;
        }
        __syncthreads();
        #pragma unroll
        for (int kk = 0; kk < 2; ++kk) {
            bf16x8 af[4], bfr[4];
            #pragma unroll
            for (int mi = 0; mi < 4; ++mi) {
                const int row = wm * 64 + mi * 16 + (lane & 15);
                const int ch  = kk * 4 + (lane >> 4);
                af[mi] = *(const bf16x8*)(As + row * 64 + ((ch ^ (row & 7)) * 8));
            }
            #pragma unroll
            for (int ni = 0; ni < 4; ++ni) {
                const int row = wn * 64 + ni * 16 + (lane & 15);
                const int ch  = kk * 4 + (lane >> 4);
                bfr[ni] = *(const bf16x8*)(Bs + row * 64 + ((ch ^ (row & 7)) * 8));
            }
            #pragma unroll
            for (int mi = 0; mi < 4; ++mi)
                #pragma unroll
                for (int ni = 0; ni < 4; ++ni)
                    acc[mi][ni] = __builtin_amdgcn_mfma_f32_16x16x32_bf16(
                        af[mi], bfr[ni], acc[mi][ni], 0, 0, 0);
        }
        __syncthreads();
    }

    const int cq = lane >> 4;
    const int cc = lane & 15;
    #pragma unroll
    for (int mi = 0; mi < 4; ++mi) {
        #pragma unroll
        for (int ni = 0; ni < 4; ++ni) {
            const int col  = j0 + wn * 64 + ni * 16 + cc;
            const int rowb = i0 + wm * 64 + mi * 16 + cq * 4;
            #pragma unroll
            for (int v = 0; v < 4; ++v)
                S[(size_t)(rowb + v) * NROWS + col] = acc[mi][ni][v];
        }
    }
}

// pass-0 dense histogram add: 1/2-digit wave-uniform leader path, else per-lane
__device__ __forceinline__ void hist_add_dense(unsigned* h, unsigned dg, int lane) {
    const unsigned d0 = (unsigned)__builtin_amdgcn_readfirstlane((int)dg);
    const unsigned long long m0 = __ballot(dg == d0);
    if (m0 == ~0ull) {
        if (lane == 0) atomicAdd(&h[d0], 64u);
    } else {
        const int l1 = __ffsll((long long)(~m0)) - 1;
        const unsigned d1 = (unsigned)__builtin_amdgcn_readlane((int)dg, l1);
        const unsigned long long m1 = __ballot(dg == d1);
        if ((m0 | m1) == ~0ull) {
            if (lane == 0)       atomicAdd(&h[d0], (unsigned)__popcll(m0));
            else if (lane == l1) atomicAdd(&h[d1], (unsigned)__popcll(m1));
        } else {
            atomicAdd(&h[dg], 1u);
        }
    }
}

// wave-autonomous per-row kernel: one wave per row, ZERO block barriers.
// Keys for the wave's 64 columns/lane live in registers (all static indices);
// per-wave private 256-bin histogram in LDS (DS ops of one wave are in-order).
// NOTE: launch bound is (256, 2) -- capping at 4 waves/SIMD (R5) forced a
// 64-VGPR allocation and spilled the whole key array (55 MB scratch writes).
__global__ __launch_bounds__(256, 2) void rowsel_wave_kernel(
        const float* __restrict__ S,
        const float* __restrict__ sq,
        const unsigned char* __restrict__ lab8,
        float* __restrict__ out)
{
    __shared__ unsigned hist[4][256];

    const int tid  = threadIdx.x;
    const int lane = tid & 63;
    const int w    = tid >> 6;
    const int row  = blockIdx.x * 4 + w;

    const float4*   S4 = (const float4*)(S + (size_t)row * NROWS);
    const float4*   Q4 = (const float4*)sq;
    const unsigned* L4 = (const unsigned*)lab8;
    unsigned* hw = &hist[w][0];

    // zero my wave's histogram (wave-private)
    ((uint4*)hw)[lane] = make_uint4(0u, 0u, 0u, 0u);

    // ---- load row, build keys (registers), Z, fused pass-0 histogram ----
    unsigned u[16][4];
    float z = 0.f;
    #pragma unroll
    for (int c = 0; c < 16; ++c) {
        const float4 v = S4[c * 64 + lane];
        const float4 q = Q4[c * 64 + lane];
        const int jb = c * 256 + lane * 4;
        u[c][0] = fkey(fmaf(-2.f, v.x, q.x));
        u[c][1] = fkey(fmaf(-2.f, v.y, q.y));
        u[c][2] = fkey(fmaf(-2.f, v.z, q.z));
        u[c][3] = fkey(fmaf(-2.f, v.w, q.w));
        z += (jb + 0 == row) ? 0.f : __expf(10.f * v.x);
        z += (jb + 1 == row) ? 0.f : __expf(10.f * v.y);
        z += (jb + 2 == row) ? 0.f : __expf(10.f * v.z);
        z += (jb + 3 == row) ? 0.f : __expf(10.f * v.w);
        hist_add_dense(hw, u[c][0] >> 24, lane);
        hist_add_dense(hw, u[c][1] >> 24, lane);
        hist_add_dense(hw, u[c][2] >> 24, lane);
        hist_add_dense(hw, u[c][3] >> 24, lane);
    }
    #pragma unroll
    for (int m = 1; m < 64; m <<= 1) z += __shfl_xor(z, m, 64);

    // ---- 4 radix passes: wave-local suffix scan, select threshold digit ----
    unsigned P = 0u, K = 128u;
    #pragma unroll
    for (int pass = 0; pass < 4; ++pass) {
        const int shift = 24 - 8 * pass;
        if (pass > 0) {
            ((uint4*)hw)[lane] = make_uint4(0u, 0u, 0u, 0u);
            #pragma unroll
            for (int c = 0; c < 16; ++c)
                #pragma unroll
                for (int e = 0; e < 4; ++e) {
                    const unsigned uu = u[c][e];
                    if (((uu ^ P) >> (shift + 8)) == 0u)
                        atomicAdd(&hw[(uu >> shift) & 255u], 1u);
                }
        }
        // read my 4 bins, lane-local + wave suffix scan
        const uint4 h = ((const uint4*)hw)[lane];
        const unsigned s3 = h.w;
        const unsigned s2 = h.z + s3;
        const unsigned s1 = h.y + s2;
        const unsigned s0 = h.x + s1;                 // lane total
        unsigned x = s0;
        #pragma unroll
        for (int d = 1; d < 64; d <<= 1) {
            const unsigned y = __shfl_down(x, d, 64);
            if (lane + d < 64) x += y;
        }
        const unsigned E = x - s0;                    // sum over lanes > lane
        unsigned pk = 0u;
        {
            const unsigned Sv0 = E + s0, Sv1 = E + s1, Sv2 = E + s2, Sv3 = E + s3;
            if (Sv0 >= K && Sv0 - h.x < K) pk = ((unsigned)(lane*4+0) << 16) | (K - (Sv0 - h.x));
            if (Sv1 >= K && Sv1 - h.y < K) pk = ((unsigned)(lane*4+1) << 16) | (K - (Sv1 - h.y));
            if (Sv2 >= K && Sv2 - h.z < K) pk = ((unsigned)(lane*4+2) << 16) | (K - (Sv2 - h.z));
            if (Sv3 >= K && Sv3 - h.w < K) pk = ((unsigned)(lane*4+3) << 16) | (K - (Sv3 - h.w));
        }
        #pragma unroll
        for (int m = 1; m < 64; m <<= 1) pk |= __shfl_xor(pk, m, 64);
        P |= (pk >> 16) << shift;
        K  = pk & 0xFFFFu;
    }

    // ---- tie ranks (lane-major order) ----
    int tcnt = 0;
    #pragma unroll
    for (int c = 0; c < 16; ++c)
        #pragma unroll
        for (int e = 0; e < 4; ++e) tcnt += (u[c][e] == P) ? 1 : 0;
    int p = tcnt;
    #pragma unroll
    for (int d = 1; d < 64; d <<= 1) {
        const int o = __shfl_up(p, d, 64);
        if (lane >= d) p += o;
    }
    int t = p - tcnt;                                 // exclusive prefix

    // ---- accumulate over selected & same-class & j != row ----
    const unsigned my = lab8[row];
    float sd = 0.f; int cnt = 0;
    #pragma unroll
    for (int c = 0; c < 16; ++c) {
        const float4 q = Q4[c * 64 + lane];
        float qa[4]; *(float4*)qa = q;
        const unsigned lw = L4[c * 64 + lane];
        const int jb = c * 256 + lane * 4;
        #pragma unroll
        for (int e = 0; e < 4; ++e) {
            const unsigned uu = u[c][e];
            bool sel = (uu > P);
            if (uu == P) { sel = (t < (int)K); ++t; }
            if (sel && (jb + e != row) && (((lw >> (8 * e)) & 255u) == my)) {
                ++cnt;
                sd += 0.5f * (qa[e] - unfkey(uu));
            }
        }
    }
    #pragma unroll
    for (int m = 1; m < 64; m <<= 1) {
        sd  += __shfl_xor(sd, m, 64);
        cnt += __shfl_xor(cnt, m, 64);
    }
    if (lane == 0 && cnt > 0) {
        const float mlpp = (10.f * sd) / (float)cnt - __logf(z);
        atomicAdd(out, -(0.1f / 0.07f) * mlpp * (1.f / (float)NROWS));
    }
}

// ===========================================================================
// FALLBACK PATH (small d_ws): R2 fused kernels (verified correct)
// ===========================================================================

__global__ void prep_kernel(const float* __restrict__ feat,
                            const int* __restrict__ labels,
                            float* __restrict__ fn,
                            float* __restrict__ sq,
                            unsigned char* __restrict__ lab8,
                            float* __restrict__ out)
{
    const int row  = blockIdx.x * 4 + (threadIdx.x >> 6);
    const int lane = threadIdx.x & 63;
    float4 x = ((const float4*)feat)[(size_t)row * 64 + lane];
    float ss = x.x*x.x + x.y*x.y + x.z*x.z + x.w*x.w;
    #pragma unroll
    for (int m = 1; m < 64; m <<= 1) ss += __shfl_xor(ss, m, 64);
    const float nrm = sqrtf(ss);
    float4 f; f.x = x.x/nrm; f.y = x.y/nrm; f.z = x.z/nrm; f.w = x.w/nrm;
    ((float4*)fn)[(size_t)row * 64 + lane] = f;
    float s2 = f.x*f.x + f.y*f.y + f.z*f.z + f.w*f.w;
    #pragma unroll
    for (int m = 1; m < 64; m <<= 1) s2 += __shfl_xor(s2, m, 64);
    if (lane == 0) {
        sq[row]  = s2;
        lab8[row] = (unsigned char)labels[row & HALF_MASK];
    }
    if (blockIdx.x == 0 && threadIdx.x == 0) out[0] = 0.0f;
}

#define R 4
__global__ __launch_bounds__(BLOCK, 3) void rowloss_kernel(
        const float* __restrict__ fn,
        const float* __restrict__ sq,
        const unsigned char* __restrict__ lab8,
        float* __restrict__ out)
{
    __shared__ __align__(16) float fi[R][DIM];
    __shared__ unsigned hist[R * 256];
    __shared__ float    wz[R][4];
    __shared__ unsigned wsc[R][4];
    __shared__ unsigned selT[R], selK[R];
    __shared__ float    wsd[R][4];
    __shared__ int      wcnt[R][4];

    const int tid  = threadIdx.x;
    const int lane = tid & 63;
    const int wv   = tid >> 6;
    const int i0   = blockIdx.x * R;
    const int j0   = tid * 16;

    for (int idx = tid; idx < R * DIM; idx += BLOCK)
        fi[idx >> 8][idx & 255] = fn[(size_t)i0 * DIM + idx];
    __syncthreads();

    const float4* fn4 = (const float4*)fn;
    const float4* fi4 = (const float4*)&fi[0][0];

    float acc[16][R];
    #pragma unroll
    for (int jj = 0; jj < 16; ++jj)
        #pragma unroll
        for (int r = 0; r < R; ++r) acc[jj][r] = 0.0f;

    for (int c = 0; c < 32; ++c) {
        float fir[R][8];
        #pragma unroll
        for (int r = 0; r < R; ++r) {
            float4 a = fi4[r * 64 + c * 2];
            float4 b = fi4[r * 64 + c * 2 + 1];
            fir[r][0] = a.x; fir[r][1] = a.y; fir[r][2] = a.z; fir[r][3] = a.w;
            fir[r][4] = b.x; fir[r][5] = b.y; fir[r][6] = b.z; fir[r][7] = b.w;
        }
        #pragma unroll
        for (int jj = 0; jj < 16; ++jj) {
            const float4* pp = fn4 + (size_t)(j0 + jj) * 64 + c * 2;
            float4 x = pp[0];
            float4 y = pp[1];
            #pragma unroll
            for (int r = 0; r < R; ++r) {
                float s = acc[jj][r];
                s = fmaf(x.x, fir[r][0], s); s = fmaf(x.y, fir[r][1], s);
                s = fmaf(x.z, fir[r][2], s); s = fmaf(x.w, fir[r][3], s);
                s = fmaf(y.x, fir[r][4], s); s = fmaf(y.y, fir[r][5], s);
                s = fmaf(y.z, fir[r][6], s); s = fmaf(y.w, fir[r][7], s);
                acc[jj][r] = s;
            }
        }
    }

    float sqr[16];
    #pragma unroll
    for (int k = 0; k < 16; ++k) sqr[k] = sq[j0 + k];

    float lzr[R];
    {
        float zloc[R];
        #pragma unroll
        for (int r = 0; r < R; ++r) {
            const int ir = i0 + r;
            float z = 0.0f;
            #pragma unroll
            for (int k = 0; k < 16; ++k) {
                float e = __expf(10.0f * acc[k][r]);
                z += (j0 + k == ir) ? 0.0f : e;
            }
            zloc[r] = z;
        }
        #pragma unroll
        for (int r = 0; r < R; ++r) {
            float z = zloc[r];
            #pragma unroll
            for (int m = 1; m < 64; m <<= 1) z += __shfl_xor(z, m, 64);
            if (lane == 0) wz[r][wv] = z;
        }
        __syncthreads();
        #pragma unroll
        for (int r = 0; r < R; ++r)
            lzr[r] = __logf(wz[r][0] + wz[r][1] + wz[r][2] + wz[r][3]);
    }

    unsigned Pr[R] = {0, 0, 0, 0};
    unsigned Kr[R] = {128u, 128u, 128u, 128u};
    #pragma unroll
    for (int pass = 0; pass < 4; ++pass) {
        const int shift = 24 - 8 * pass;
        #pragma unroll
        for (int r = 0; r < R; ++r) hist[r * 256 + tid] = 0u;
        __syncthreads();
        #pragma unroll
        for (int r = 0; r < R; ++r) {
            #pragma unroll
            for (int k = 0; k < 16; ++k) {
                unsigned uu = fkey(fmaf(-2.0f, acc[k][r], sqr[k]));
                bool act = (pass == 0) ||
                    (((unsigned long long)(uu ^ Pr[r]) >> (shift + 8)) == 0ull);
                if (act) atomicAdd(&hist[r * 256 + ((uu >> shift) & 255u)], 1u);
            }
        }
        __syncthreads();
        unsigned g[R], Pv[R];
        #pragma unroll
        for (int r = 0; r < R; ++r) { g[r] = hist[r * 256 + (255 - tid)]; Pv[r] = g[r]; }
        #pragma unroll
        for (int dd = 1; dd < 64; dd <<= 1) {
            #pragma unroll
            for (int r = 0; r < R; ++r) {
                unsigned o = __shfl_up(Pv[r], dd, 64);
                if (lane >= dd) Pv[r] += o;
            }
        }
        if (lane == 63) {
            #pragma unroll
            for (int r = 0; r < R; ++r) wsc[r][wv] = Pv[r];
        }
        __syncthreads();
        #pragma unroll
        for (int r = 0; r < R; ++r) {
            unsigned off = 0;
            #pragma unroll
            for (int ww = 0; ww < 4; ++ww) if (ww < wv) off += wsc[r][ww];
            const unsigned Sv = Pv[r] + off;
            const unsigned Sn = Sv - g[r];
            if (Sv >= Kr[r] && Sn < Kr[r]) {
                selT[r] = Pr[r] | ((unsigned)(255 - tid) << shift);
                selK[r] = Kr[r] - Sn;
            }
        }
        __syncthreads();
        #pragma unroll
        for (int r = 0; r < R; ++r) { Pr[r] = selT[r]; Kr[r] = selK[r]; }
        __syncthreads();
    }

    int tb[R];
    {
        int tcr[R], Pt[R];
        #pragma unroll
        for (int r = 0; r < R; ++r) {
            int c = 0;
            #pragma unroll
            for (int k = 0; k < 16; ++k)
                if (fkey(fmaf(-2.0f, acc[k][r], sqr[k])) == Pr[r]) c++;
            tcr[r] = c; Pt[r] = c;
        }
        #pragma unroll
        for (int dd = 1; dd < 64; dd <<= 1) {
            #pragma unroll
            for (int r = 0; r < R; ++r) {
                int o = __shfl_up(Pt[r], dd, 64);
                if (lane >= dd) Pt[r] += o;
            }
        }
        if (lane == 63) {
            #pragma unroll
            for (int r = 0; r < R; ++r) wsc[r][wv] = (unsigned)Pt[r];
        }
        __syncthreads();
        #pragma unroll
        for (int r = 0; r < R; ++r) {
            int off = 0;
            #pragma unroll
            for (int ww = 0; ww < 4; ++ww) if (ww < wv) off += (int)wsc[r][ww];
            tb[r] = Pt[r] + off - tcr[r];
        }
    }

    const uint4 labv = ((const uint4*)lab8)[tid];
    const unsigned labw[4] = {labv.x, labv.y, labv.z, labv.w};

    #pragma unroll
    for (int r = 0; r < R; ++r) {
        const int ir = i0 + r;
        const unsigned my = lab8[ir];
        float sd = 0.0f; int cnt = 0; int t = tb[r];
        #pragma unroll
        for (int k = 0; k < 16; ++k) {
            const unsigned uu = fkey(fmaf(-2.0f, acc[k][r], sqr[k]));
            bool sel = (uu > Pr[r]);
            if (uu == Pr[r]) { sel = (t < (int)Kr[r]); t++; }
            const unsigned lj = (labw[k >> 2] >> ((k & 3) * 8)) & 255u;
            if (sel && (j0 + k != ir) && lj == my) { cnt++; sd += acc[k][r]; }
        }
        #pragma unroll
        for (int m = 1; m < 64; m <<= 1) {
            sd  += __shfl_xor(sd, m, 64);
            cnt += __shfl_xor(cnt, m, 64);
        }
        if (lane == 0) { wsd[r][wv] = sd; wcnt[r][wv] = cnt; }
    }
    __syncthreads();

    if (tid < R) {
        const int r = tid;
        const int c = wcnt[r][0] + wcnt[r][1] + wcnt[r][2] + wcnt[r][3];
        if (c > 0) {
            const float sd = wsd[r][0] + wsd[r][1] + wsd[r][2] + wsd[r][3];
            const float mlpp = (10.0f * sd) / (float)c - lzr[r];
            atomicAdd(out, -(0.1f / 0.07f) * mlpp * (1.0f / (float)NROWS));
        }
    }
}

// ===========================================================================

extern "C" void kernel_launch(void* const* d_in, const int* in_sizes, int n_in,
                              void* d_out, int out_size, void* d_ws, size_t ws_size,
                              hipStream_t stream) {
    (void)in_sizes; (void)n_in; (void)out_size;
    const float* feat  = (const float*)d_in[0];
    const int* labels  = (const int*)d_in[1];
    float* out = (float*)d_out;

    const size_t offS = 0;                                   // 4096*4096 f32
    const size_t offF = (size_t)NROWS * NROWS * 4;           // fn bf16
    const size_t offQ = offF + (size_t)NROWS * DIM * 2;      // sq f32
    const size_t offL = offQ + (size_t)NROWS * 4;            // labels u8
    const size_t need = offL + (size_t)NROWS;

    if (ws_size >= need) {
        float* S   = (float*)((char*)d_ws + offS);
        short* fnb = (short*)((char*)d_ws + offF);
        float* sq  = (float*)((char*)d_ws + offQ);
        unsigned char* lab8 = (unsigned char*)((char*)d_ws + offL);

        prep_bf16_kernel<<<NROWS / 4, BLOCK, 0, stream>>>(feat, labels, fnb, sq, lab8, out);
        gram_kernel<<<(NROWS / 128) * (NROWS / 128), BLOCK, 0, stream>>>(fnb, S);
        rowsel_wave_kernel<<<NROWS / 4, BLOCK, 0, stream>>>(S, sq, lab8, out);
    } else {
        float* fn = (float*)d_ws;
        float* sq = fn + (size_t)NROWS * DIM;
        unsigned char* lab8 = (unsigned char*)(sq + NROWS);

        prep_kernel<<<NROWS / 4, BLOCK, 0, stream>>>(feat, labels, fn, sq, lab8, out);
        rowloss_kernel<<<NROWS / R, BLOCK, 0, stream>>>(fn, sq, lab8, out);
    }
}

// Round 7
// 98.770 us; speedup vs baseline: 1.3172x; 1.1553x over previous
//
#include <hip/hip_runtime.h>
#include <hip/hip_bf16.h>
#include <math.h>

#define NROWS 4096
#define DIM   256
#define HALF_MASK 2047
#define BLOCK 256

typedef __attribute__((ext_vector_type(8))) short bf16x8;
typedef __attribute__((ext_vector_type(4))) float f32x4;

// order-preserving float -> uint transform (ascending uint == ascending float)
__device__ __forceinline__ unsigned fkey(float f) {
    unsigned u = __float_as_uint(f);
    return (u & 0x80000000u) ? ~u : (u | 0x80000000u);
}
// inverse of fkey
__device__ __forceinline__ float unfkey(unsigned u) {
    unsigned b = (u & 0x80000000u) ? (u & 0x7fffffffu) : ~u;
    return __uint_as_float(b);
}

// ===========================================================================
// FAST PATH: prep -> bf16 MFMA Gram -> 2-wave-per-row select
// ===========================================================================

__global__ void prep_bf16_kernel(const float* __restrict__ feat,
                                 const int* __restrict__ labels,
                                 short* __restrict__ fnb,
                                 float* __restrict__ sq,
                                 unsigned char* __restrict__ lab8,
                                 float* __restrict__ out)
{
    const int row  = blockIdx.x * 4 + (threadIdx.x >> 6);
    const int lane = threadIdx.x & 63;
    float4 x = ((const float4*)feat)[(size_t)row * 64 + lane];
    float ss = x.x*x.x + x.y*x.y + x.z*x.z + x.w*x.w;
    #pragma unroll
    for (int m = 1; m < 64; m <<= 1) ss += __shfl_xor(ss, m, 64);
    const float nrm = sqrtf(ss);
    float4 f; f.x = x.x/nrm; f.y = x.y/nrm; f.z = x.z/nrm; f.w = x.w/nrm;

    union { __hip_bfloat16 b; unsigned short s; } cv[4];
    cv[0].b = __float2bfloat16(f.x); cv[1].b = __float2bfloat16(f.y);
    cv[2].b = __float2bfloat16(f.z); cv[3].b = __float2bfloat16(f.w);
    ushort4 h; h.x = cv[0].s; h.y = cv[1].s; h.z = cv[2].s; h.w = cv[3].s;
    ((ushort4*)fnb)[(size_t)row * 64 + lane] = h;

    float s2 = f.x*f.x + f.y*f.y + f.z*f.z + f.w*f.w;
    #pragma unroll
    for (int m = 1; m < 64; m <<= 1) s2 += __shfl_xor(s2, m, 64);
    if (lane == 0) {
        sq[row]   = s2;                       // used by fallback path only
        lab8[row] = (unsigned char)labels[row & HALF_MASK];
    }
    if (blockIdx.x == 0 && threadIdx.x == 0) out[0] = 0.0f;
}

// Gram: S = fn * fn^T (4096x4096, K=256), bf16 MFMA 16x16x32, fp32 out.
__global__ __launch_bounds__(256) void gram_kernel(
        const short* __restrict__ fnb, float* __restrict__ S)
{
    __shared__ __align__(16) short As[128 * 64];
    __shared__ __align__(16) short Bs[128 * 64];

    const int tid  = threadIdx.x;
    const int lane = tid & 63;
    const int wv   = tid >> 6;
    const int wm   = wv >> 1, wn = wv & 1;
    const int bi   = blockIdx.x >> 5;
    const int bj   = blockIdx.x & 31;
    const int i0   = bi * 128, j0 = bj * 128;

    f32x4 acc[4][4];
    const f32x4 zero = {0.f, 0.f, 0.f, 0.f};
    #pragma unroll
    for (int a = 0; a < 4; ++a)
        #pragma unroll
        for (int b = 0; b < 4; ++b) acc[a][b] = zero;

    const int srow   = tid >> 3;
    const int schunk = tid & 7;

    for (int kt = 0; kt < 4; ++kt) {
        #pragma unroll
        for (int is = 0; is < 4; ++is) {
            const int row = is * 32 + srow;
            const size_t gsrc = (size_t)kt * 64 + schunk * 8;
            uint4 va = *(const uint4*)(fnb + (size_t)(i0 + row) * DIM + gsrc);
            uint4 vb = *(const uint4*)(fnb + (size_t)(j0 + row) * DIM + gsrc);
            const int dst = row * 64 + ((schunk ^ (row & 7)) * 8);
            *(uint4*)(As + dst) = va;
            *(uint4*)(Bs + dst) = vb;
        }
        __syncthreads();
        #pragma unroll
        for (int kk = 0; kk < 2; ++kk) {
            bf16x8 af[4], bfr[4];
            #pragma unroll
            for (int mi = 0; mi < 4; ++mi) {
                const int row = wm * 64 + mi * 16 + (lane & 15);
                const int ch  = kk * 4 + (lane >> 4);
                af[mi] = *(const bf16x8*)(As + row * 64 + ((ch ^ (row & 7)) * 8));
            }
            #pragma unroll
            for (int ni = 0; ni < 4; ++ni) {
                const int row = wn * 64 + ni * 16 + (lane & 15);
                const int ch  = kk * 4 + (lane >> 4);
                bfr[ni] = *(const bf16x8*)(Bs + row * 64 + ((ch ^ (row & 7)) * 8));
            }
            #pragma unroll
            for (int mi = 0; mi < 4; ++mi)
                #pragma unroll
                for (int ni = 0; ni < 4; ++ni)
                    acc[mi][ni] = __builtin_amdgcn_mfma_f32_16x16x32_bf16(
                        af[mi], bfr[ni], acc[mi][ni], 0, 0, 0);
        }
        __syncthreads();
    }

    const int cq = lane >> 4;
    const int cc = lane & 15;
    #pragma unroll
    for (int mi = 0; mi < 4; ++mi) {
        #pragma unroll
        for (int ni = 0; ni < 4; ++ni) {
            const int col  = j0 + wn * 64 + ni * 16 + cc;
            const int rowb = i0 + wm * 64 + mi * 16 + cq * 4;
            #pragma unroll
            for (int v = 0; v < 4; ++v)
                S[(size_t)(rowb + v) * NROWS + col] = acc[mi][ni][v];
        }
    }
}

// pass-0 dense histogram add: 1/2-digit wave-uniform leader path, else per-lane
__device__ __forceinline__ void hist_add_dense(unsigned* h, unsigned dg, int lane) {
    const unsigned d0 = (unsigned)__builtin_amdgcn_readfirstlane((int)dg);
    const unsigned long long m0 = __ballot(dg == d0);
    if (m0 == ~0ull) {
        if (lane == 0) atomicAdd(&h[d0], 64u);
    } else {
        const int l1 = __ffsll((long long)(~m0)) - 1;
        const unsigned d1 = (unsigned)__builtin_amdgcn_readlane((int)dg, l1);
        const unsigned long long m1 = __ballot(dg == d1);
        if ((m0 | m1) == ~0ull) {
            if (lane == 0)       atomicAdd(&h[d0], (unsigned)__popcll(m0));
            else if (lane == l1) atomicAdd(&h[d1], (unsigned)__popcll(m1));
        } else {
            atomicAdd(&h[dg], 1u);
        }
    }
}

// suffix-scan a 256-bin histogram within one wave, pick threshold digit
__device__ __forceinline__ void radix_scan(const unsigned* hb, int lane,
                                           unsigned& P, unsigned& K, int shift) {
    const uint4 h = ((const uint4*)hb)[lane];
    const unsigned s3 = h.w;
    const unsigned s2 = h.z + s3;
    const unsigned s1 = h.y + s2;
    const unsigned s0 = h.x + s1;
    unsigned x = s0;
    #pragma unroll
    for (int d = 1; d < 64; d <<= 1) {
        const unsigned y = __shfl_down(x, d, 64);
        if (lane + d < 64) x += y;
    }
    const unsigned E = x - s0;                    // sum over lanes > lane
    unsigned pk = 0u;
    const unsigned Sv0 = E + s0, Sv1 = E + s1, Sv2 = E + s2, Sv3 = E + s3;
    if (Sv0 >= K && Sv0 - h.x < K) pk = ((unsigned)(lane*4+0) << 16) | (K - (Sv0 - h.x));
    if (Sv1 >= K && Sv1 - h.y < K) pk = ((unsigned)(lane*4+1) << 16) | (K - (Sv1 - h.y));
    if (Sv2 >= K && Sv2 - h.z < K) pk = ((unsigned)(lane*4+2) << 16) | (K - (Sv2 - h.z));
    if (Sv3 >= K && Sv3 - h.w < K) pk = ((unsigned)(lane*4+3) << 16) | (K - (Sv3 - h.w));
    #pragma unroll
    for (int m = 1; m < 64; m <<= 1) pk |= __shfl_xor(pk, m, 64);
    P |= (pk >> 16) << shift;
    K  = pk & 0xFFFFu;
}

// 2 waves per row (each owns 2048 cols; keys in 32 VGPRs/lane), one shared
// 256-bin histogram per row, double-buffered -> 2 barriers/pass, 10 total.
// Key = fkey(1 - 2*dot): sq_j == 1 +- 2e-7 for normalized rows, so dropping it
// changes only exact-tie ordering (impact <=1e-7 on the scalar loss). The
// selected dot is recovered bit-exactly from the key: d = 0.5*(1 - unfkey(u)).
__global__ __launch_bounds__(BLOCK) void rowsel2_kernel(
        const float* __restrict__ S,
        const unsigned char* __restrict__ lab8,
        float* __restrict__ out)
{
    __shared__ unsigned hist[2][2][256];     // [row-pair][buf][bin]
    __shared__ float    zb[2][2];
    __shared__ unsigned tieb[2][2];
    __shared__ float    sdb[2][2];
    __shared__ int      cntb[2][2];

    const int tid  = threadIdx.x;
    const int lane = tid & 63;
    const int w    = tid >> 6;     // 0..3
    const int rp   = w >> 1;       // which row of the block's pair
    const int half = w & 1;        // which column half
    const int row  = blockIdx.x * 2 + rp;
    const int jbase = half * 2048;

    const float4*   S4 = (const float4*)(S + (size_t)row * NROWS) + half * 512;
    const unsigned* L4 = (const unsigned*)lab8 + half * 512;
    unsigned* h0 = &hist[rp][0][0];
    unsigned* h1 = &hist[rp][1][0];

    // zero bufA (each wave zeroes its half of its row's buffer)
    ((uint2*)(h0 + half * 128))[lane] = make_uint2(0u, 0u);

    // ---- pure load + key-build + Z loop (no LDS -> loads can pipeline) ----
    unsigned u[8][4];
    float z = 0.f;
    #pragma unroll
    for (int c = 0; c < 8; ++c) {
        const float4 v = S4[c * 64 + lane];
        const int jb = jbase + c * 256 + lane * 4;
        u[c][0] = fkey(fmaf(-2.f, v.x, 1.0f));
        u[c][1] = fkey(fmaf(-2.f, v.y, 1.0f));
        u[c][2] = fkey(fmaf(-2.f, v.z, 1.0f));
        u[c][3] = fkey(fmaf(-2.f, v.w, 1.0f));
        z += (jb + 0 == row) ? 0.f : __expf(10.f * v.x);
        z += (jb + 1 == row) ? 0.f : __expf(10.f * v.y);
        z += (jb + 2 == row) ? 0.f : __expf(10.f * v.z);
        z += (jb + 3 == row) ? 0.f : __expf(10.f * v.w);
    }
    #pragma unroll
    for (int m = 1; m < 64; m <<= 1) z += __shfl_xor(z, m, 64);
    if (lane == 0) zb[rp][half] = z;

    __syncthreads();                                   // B0: zeros + z visible

    // ---- pass 0: ballot-compressed histogram of the top byte ----
    #pragma unroll
    for (int c = 0; c < 8; ++c) {
        hist_add_dense(h0, u[c][0] >> 24, lane);
        hist_add_dense(h0, u[c][1] >> 24, lane);
        hist_add_dense(h0, u[c][2] >> 24, lane);
        hist_add_dense(h0, u[c][3] >> 24, lane);
    }
    __syncthreads();                                   // B1: atomics done

    unsigned P = 0u, K = 128u;
    radix_scan(h0, lane, P, K, 24);
    ((uint2*)(h1 + half * 128))[lane] = make_uint2(0u, 0u);   // zero bufB

    // ---- passes 1..3, double-buffered ----
    #pragma unroll
    for (int pass = 1; pass < 4; ++pass) {
        const int shift = 24 - 8 * pass;
        unsigned* hb = (pass & 1) ? h1 : h0;
        unsigned* hn = (pass & 1) ? h0 : h1;
        __syncthreads();                               // zeros visible
        #pragma unroll
        for (int c = 0; c < 8; ++c)
            #pragma unroll
            for (int e = 0; e < 4; ++e) {
                const unsigned uu = u[c][e];
                if (((uu ^ P) >> (shift + 8)) == 0u)
                    atomicAdd(&hb[(uu >> shift) & 255u], 1u);
            }
        __syncthreads();                               // atomics done
        radix_scan(hb, lane, P, K, shift);
        if (pass < 3)
            ((uint2*)(hn + half * 128))[lane] = make_uint2(0u, 0u);
    }

    // ---- tie ranks: wave prefix + cross-wave offset ----
    int tcnt = 0;
    #pragma unroll
    for (int c = 0; c < 8; ++c)
        #pragma unroll
        for (int e = 0; e < 4; ++e) tcnt += (u[c][e] == P) ? 1 : 0;
    int p = tcnt;
    #pragma unroll
    for (int d = 1; d < 64; d <<= 1) {
        const int o = __shfl_up(p, d, 64);
        if (lane >= d) p += o;
    }
    if (lane == 63) tieb[rp][half] = (unsigned)p;
    __syncthreads();                                   // B8
    int t = p - tcnt + ((half == 1) ? (int)tieb[rp][0] : 0);

    // ---- accumulate over selected & same-class & j != row ----
    const unsigned my = lab8[row];
    float sd = 0.f; int cnt = 0;
    #pragma unroll
    for (int c = 0; c < 8; ++c) {
        const unsigned lw = L4[c * 64 + lane];
        const int jb = jbase + c * 256 + lane * 4;
        #pragma unroll
        for (int e = 0; e < 4; ++e) {
            const unsigned uu = u[c][e];
            bool sel = (uu > P);
            if (uu == P) { sel = (t < (int)K); ++t; }
            if (sel && (jb + e != row) && (((lw >> (8 * e)) & 255u) == my)) {
                ++cnt;
                sd += 0.5f * (1.0f - unfkey(uu));
            }
        }
    }
    #pragma unroll
    for (int m = 1; m < 64; m <<= 1) {
        sd  += __shfl_xor(sd, m, 64);
        cnt += __shfl_xor(cnt, m, 64);
    }
    if (lane == 0) { sdb[rp][half] = sd; cntb[rp][half] = cnt; }
    __syncthreads();                                   // B9

    if (lane == 0 && half == 0) {
        const int c = cntb[rp][0] + cntb[rp][1];
        if (c > 0) {
            const float s = sdb[rp][0] + sdb[rp][1];
            const float Z = zb[rp][0] + zb[rp][1];
            const float mlpp = (10.f * s) / (float)c - __logf(Z);
            atomicAdd(out, -(0.1f / 0.07f) * mlpp * (1.f / (float)NROWS));
        }
    }
}

// ===========================================================================
// FALLBACK PATH (small d_ws): R2 fused kernels (verified correct)
// ===========================================================================

__global__ void prep_kernel(const float* __restrict__ feat,
                            const int* __restrict__ labels,
                            float* __restrict__ fn,
                            float* __restrict__ sq,
                            unsigned char* __restrict__ lab8,
                            float* __restrict__ out)
{
    const int row  = blockIdx.x * 4 + (threadIdx.x >> 6);
    const int lane = threadIdx.x & 63;
    float4 x = ((const float4*)feat)[(size_t)row * 64 + lane];
    float ss = x.x*x.x + x.y*x.y + x.z*x.z + x.w*x.w;
    #pragma unroll
    for (int m = 1; m < 64; m <<= 1) ss += __shfl_xor(ss, m, 64);
    const float nrm = sqrtf(ss);
    float4 f; f.x = x.x/nrm; f.y = x.y/nrm; f.z = x.z/nrm; f.w = x.w/nrm;
    ((float4*)fn)[(size_t)row * 64 + lane] = f;
    float s2 = f.x*f.x + f.y*f.y + f.z*f.z + f.w*f.w;
    #pragma unroll
    for (int m = 1; m < 64; m <<= 1) s2 += __shfl_xor(s2, m, 64);
    if (lane == 0) {
        sq[row]  = s2;
        lab8[row] = (unsigned char)labels[row & HALF_MASK];
    }
    if (blockIdx.x == 0 && threadIdx.x == 0) out[0] = 0.0f;
}

#define R 4
__global__ __launch_bounds__(BLOCK, 3) void rowloss_kernel(
        const float* __restrict__ fn,
        const float* __restrict__ sq,
        const unsigned char* __restrict__ lab8,
        float* __restrict__ out)
{
    __shared__ __align__(16) float fi[R][DIM];
    __shared__ unsigned hist[R * 256];
    __shared__ float    wz[R][4];
    __shared__ unsigned wsc[R][4];
    __shared__ unsigned selT[R], selK[R];
    __shared__ float    wsd[R][4];
    __shared__ int      wcnt[R][4];

    const int tid  = threadIdx.x;
    const int lane = tid & 63;
    const int wv   = tid >> 6;
    const int i0   = blockIdx.x * R;
    const int j0   = tid * 16;

    for (int idx = tid; idx < R * DIM; idx += BLOCK)
        fi[idx >> 8][idx & 255] = fn[(size_t)i0 * DIM + idx];
    __syncthreads();

    const float4* fn4 = (const float4*)fn;
    const float4* fi4 = (const float4*)&fi[0][0];

    float acc[16][R];
    #pragma unroll
    for (int jj = 0; jj < 16; ++jj)
        #pragma unroll
        for (int r = 0; r < R; ++r) acc[jj][r] = 0.0f;

    for (int c = 0; c < 32; ++c) {
        float fir[R][8];
        #pragma unroll
        for (int r = 0; r < R; ++r) {
            float4 a = fi4[r * 64 + c * 2];
            float4 b = fi4[r * 64 + c * 2 + 1];
            fir[r][0] = a.x; fir[r][1] = a.y; fir[r][2] = a.z; fir[r][3] = a.w;
            fir[r][4] = b.x; fir[r][5] = b.y; fir[r][6] = b.z; fir[r][7] = b.w;
        }
        #pragma unroll
        for (int jj = 0; jj < 16; ++jj) {
            const float4* pp = fn4 + (size_t)(j0 + jj) * 64 + c * 2;
            float4 x = pp[0];
            float4 y = pp[1];
            #pragma unroll
            for (int r = 0; r < R; ++r) {
                float s = acc[jj][r];
                s = fmaf(x.x, fir[r][0], s); s = fmaf(x.y, fir[r][1], s);
                s = fmaf(x.z, fir[r][2], s); s = fmaf(x.w, fir[r][3], s);
                s = fmaf(y.x, fir[r][4], s); s = fmaf(y.y, fir[r][5], s);
                s = fmaf(y.z, fir[r][6], s); s = fmaf(y.w, fir[r][7], s);
                acc[jj][r] = s;
            }
        }
    }

    float sqr[16];
    #pragma unroll
    for (int k = 0; k < 16; ++k) sqr[k] = sq[j0 + k];

    float lzr[R];
    {
        float zloc[R];
        #pragma unroll
        for (int r = 0; r < R; ++r) {
            const int ir = i0 + r;
            float z = 0.0f;
            #pragma unroll
            for (int k = 0; k < 16; ++k) {
                float e = __expf(10.0f * acc[k][r]);
                z += (j0 + k == ir) ? 0.0f : e;
            }
            zloc[r] = z;
        }
        #pragma unroll
        for (int r = 0; r < R; ++r) {
            float z = zloc[r];
            #pragma unroll
            for (int m = 1; m < 64; m <<= 1) z += __shfl_xor(z, m, 64);
            if (lane == 0) wz[r][wv] = z;
        }
        __syncthreads();
        #pragma unroll
        for (int r = 0; r < R; ++r)
            lzr[r] = __logf(wz[r][0] + wz[r][1] + wz[r][2] + wz[r][3]);
    }

    unsigned Pr[R] = {0, 0, 0, 0};
    unsigned Kr[R] = {128u, 128u, 128u, 128u};
    #pragma unroll
    for (int pass = 0; pass < 4; ++pass) {
        const int shift = 24 - 8 * pass;
        #pragma unroll
        for (int r = 0; r < R; ++r) hist[r * 256 + tid] = 0u;
        __syncthreads();
        #pragma unroll
        for (int r = 0; r < R; ++r) {
            #pragma unroll
            for (int k = 0; k < 16; ++k) {
                unsigned uu = fkey(fmaf(-2.0f, acc[k][r], sqr[k]));
                bool act = (pass == 0) ||
                    (((unsigned long long)(uu ^ Pr[r]) >> (shift + 8)) == 0ull);
                if (act) atomicAdd(&hist[r * 256 + ((uu >> shift) & 255u)], 1u);
            }
        }
        __syncthreads();
        unsigned g[R], Pv[R];
        #pragma unroll
        for (int r = 0; r < R; ++r) { g[r] = hist[r * 256 + (255 - tid)]; Pv[r] = g[r]; }
        #pragma unroll
        for (int dd = 1; dd < 64; dd <<= 1) {
            #pragma unroll
            for (int r = 0; r < R; ++r) {
                unsigned o = __shfl_up(Pv[r], dd, 64);
                if (lane >= dd) Pv[r] += o;
            }
        }
        if (lane == 63) {
            #pragma unroll
            for (int r = 0; r < R; ++r) wsc[r][wv] = Pv[r];
        }
        __syncthreads();
        #pragma unroll
        for (int r = 0; r < R; ++r) {
            unsigned off = 0;
            #pragma unroll
            for (int ww = 0; ww < 4; ++ww) if (ww < wv) off += wsc[r][ww];
            const unsigned Sv = Pv[r] + off;
            const unsigned Sn = Sv - g[r];
            if (Sv >= Kr[r] && Sn < Kr[r]) {
                selT[r] = Pr[r] | ((unsigned)(255 - tid) << shift);
                selK[r] = Kr[r] - Sn;
            }
        }
        __syncthreads();
        #pragma unroll
        for (int r = 0; r < R; ++r) { Pr[r] = selT[r]; Kr[r] = selK[r]; }
        __syncthreads();
    }

    int tb[R];
    {
        int tcr[R], Pt[R];
        #pragma unroll
        for (int r = 0; r < R; ++r) {
            int c = 0;
            #pragma unroll
            for (int k = 0; k < 16; ++k)
                if (fkey(fmaf(-2.0f, acc[k][r], sqr[k])) == Pr[r]) c++;
            tcr[r] = c; Pt[r] = c;
        }
        #pragma unroll
        for (int dd = 1; dd < 64; dd <<= 1) {
            #pragma unroll
            for (int r = 0; r < R; ++r) {
                int o = __shfl_up(Pt[r], dd, 64);
                if (lane >= dd) Pt[r] += o;
            }
        }
        if (lane == 63) {
            #pragma unroll
            for (int r = 0; r < R; ++r) wsc[r][wv] = (unsigned)Pt[r];
        }
        __syncthreads();
        #pragma unroll
        for (int r = 0; r < R; ++r) {
            int off = 0;
            #pragma unroll
            for (int ww = 0; ww < 4; ++ww) if (ww < wv) off += (int)wsc[r][ww];
            tb[r] = Pt[r] + off - tcr[r];
        }
    }

    const uint4 labv = ((const uint4*)lab8)[tid];
    const unsigned labw[4] = {labv.x, labv.y, labv.z, labv.w};

    #pragma unroll
    for (int r = 0; r < R; ++r) {
        const int ir = i0 + r;
        const unsigned my = lab8[ir];
        float sd = 0.0f; int cnt = 0; int t = tb[r];
        #pragma unroll
        for (int k = 0; k < 16; ++k) {
            const unsigned uu = fkey(fmaf(-2.0f, acc[k][r], sqr[k]));
            bool sel = (uu > Pr[r]);
            if (uu == Pr[r]) { sel = (t < (int)Kr[r]); t++; }
            const unsigned lj = (labw[k >> 2] >> ((k & 3) * 8)) & 255u;
            if (sel && (j0 + k != ir) && lj == my) { cnt++; sd += acc[k][r]; }
        }
        #pragma unroll
        for (int m = 1; m < 64; m <<= 1) {
            sd  += __shfl_xor(sd, m, 64);
            cnt += __shfl_xor(cnt, m, 64);
        }
        if (lane == 0) { wsd[r][wv] = sd; wcnt[r][wv] = cnt; }
    }
    __syncthreads();

    if (tid < R) {
        const int r = tid;
        const int c = wcnt[r][0] + wcnt[r][1] + wcnt[r][2] + wcnt[r][3];
        if (c > 0) {
            const float sd = wsd[r][0] + wsd[r][1] + wsd[r][2] + wsd[r][3];
            const float mlpp = (10.0f * sd) / (float)c - lzr[r];
            atomicAdd(out, -(0.1f / 0.07f) * mlpp * (1.0f / (float)NROWS));
        }
    }
}

// ===========================================================================

extern "C" void kernel_launch(void* const* d_in, const int* in_sizes, int n_in,
                              void* d_out, int out_size, void* d_ws, size_t ws_size,
                              hipStream_t stream) {
    (void)in_sizes; (void)n_in; (void)out_size;
    const float* feat  = (const float*)d_in[0];
    const int* labels  = (const int*)d_in[1];
    float* out = (float*)d_out;

    const size_t offS = 0;                                   // 4096*4096 f32
    const size_t offF = (size_t)NROWS * NROWS * 4;           // fn bf16
    const size_t offQ = offF + (size_t)NROWS * DIM * 2;      // sq f32
    const size_t offL = offQ + (size_t)NROWS * 4;            // labels u8
    const size_t need = offL + (size_t)NROWS;

    if (ws_size >= need) {
        float* S   = (float*)((char*)d_ws + offS);
        short* fnb = (short*)((char*)d_ws + offF);
        float* sq  = (float*)((char*)d_ws + offQ);
        unsigned char* lab8 = (unsigned char*)((char*)d_ws + offL);

        prep_bf16_kernel<<<NROWS / 4, BLOCK, 0, stream>>>(feat, labels, fnb, sq, lab8, out);
        gram_kernel<<<(NROWS / 128) * (NROWS / 128), BLOCK, 0, stream>>>(fnb, S);
        rowsel2_kernel<<<NROWS / 2, BLOCK, 0, stream>>>(S, lab8, out);
    } else {
        float* fn = (float*)d_ws;
        float* sq = fn + (size_t)NROWS * DIM;
        unsigned char* lab8 = (unsigned char*)(sq + NROWS);

        prep_kernel<<<NROWS / 4, BLOCK, 0, stream>>>(feat, labels, fn, sq, lab8, out);
        rowloss_kernel<<<NROWS / R, BLOCK, 0, stream>>>(fn, sq, lab8, out);
    }
}

// Round 8
// 92.956 us; speedup vs baseline: 1.3995x; 1.0626x over previous
//
#include <hip/hip_runtime.h>
#include <hip/hip_bf16.h>
#include <math.h>

#define NROWS 4096
#define DIM   256
#define HALF_MASK 2047
#define BLOCK 256

typedef __attribute__((ext_vector_type(8))) short bf16x8;
typedef __attribute__((ext_vector_type(4))) float f32x4;

// order-preserving float -> uint transform (fallback path only)
__device__ __forceinline__ unsigned fkey(float f) {
    unsigned u = __float_as_uint(f);
    return (u & 0x80000000u) ? ~u : (u | 0x80000000u);
}

// quantized distance key: q = clamp((1-dot)*2^31), monotone increasing in
// distance. Injective down to dot deltas of ~1e-7 (ulp 128 in q units).
__device__ __forceinline__ unsigned qkey(float dot) {
    const float f = fmaf(dot, -2147483648.f, 2147483648.f);
    return (unsigned)fminf(fmaxf(f, 0.f), 4294967040.f);
}

// ===========================================================================
// FAST PATH: prep -> bf16 MFMA Gram -> quantized-radix per-row select
// ===========================================================================

__global__ void prep_bf16_kernel(const float* __restrict__ feat,
                                 const int* __restrict__ labels,
                                 short* __restrict__ fnb,
                                 float* __restrict__ sq,
                                 unsigned char* __restrict__ lab8,
                                 float* __restrict__ out)
{
    const int row  = blockIdx.x * 4 + (threadIdx.x >> 6);
    const int lane = threadIdx.x & 63;
    float4 x = ((const float4*)feat)[(size_t)row * 64 + lane];
    float ss = x.x*x.x + x.y*x.y + x.z*x.z + x.w*x.w;
    #pragma unroll
    for (int m = 1; m < 64; m <<= 1) ss += __shfl_xor(ss, m, 64);
    const float nrm = sqrtf(ss);
    float4 f; f.x = x.x/nrm; f.y = x.y/nrm; f.z = x.z/nrm; f.w = x.w/nrm;

    union { __hip_bfloat16 b; unsigned short s; } cv[4];
    cv[0].b = __float2bfloat16(f.x); cv[1].b = __float2bfloat16(f.y);
    cv[2].b = __float2bfloat16(f.z); cv[3].b = __float2bfloat16(f.w);
    ushort4 h; h.x = cv[0].s; h.y = cv[1].s; h.z = cv[2].s; h.w = cv[3].s;
    ((ushort4*)fnb)[(size_t)row * 64 + lane] = h;

    float s2 = f.x*f.x + f.y*f.y + f.z*f.z + f.w*f.w;
    #pragma unroll
    for (int m = 1; m < 64; m <<= 1) s2 += __shfl_xor(s2, m, 64);
    if (lane == 0) {
        sq[row]   = s2;                       // used by fallback path only
        lab8[row] = (unsigned char)labels[row & HALF_MASK];
    }
    if (blockIdx.x == 0 && threadIdx.x == 0) out[0] = 0.0f;
}

// Gram: S = fn * fn^T (4096x4096, K=256), bf16 MFMA 16x16x32, fp32 out.
__global__ __launch_bounds__(256) void gram_kernel(
        const short* __restrict__ fnb, float* __restrict__ S)
{
    __shared__ __align__(16) short As[128 * 64];
    __shared__ __align__(16) short Bs[128 * 64];

    const int tid  = threadIdx.x;
    const int lane = tid & 63;
    const int wv   = tid >> 6;
    const int wm   = wv >> 1, wn = wv & 1;
    const int bi   = blockIdx.x >> 5;
    const int bj   = blockIdx.x & 31;
    const int i0   = bi * 128, j0 = bj * 128;

    f32x4 acc[4][4];
    const f32x4 zero = {0.f, 0.f, 0.f, 0.f};
    #pragma unroll
    for (int a = 0; a < 4; ++a)
        #pragma unroll
        for (int b = 0; b < 4; ++b) acc[a][b] = zero;

    const int srow   = tid >> 3;
    const int schunk = tid & 7;

    for (int kt = 0; kt < 4; ++kt) {
        #pragma unroll
        for (int is = 0; is < 4; ++is) {
            const int row = is * 32 + srow;
            const size_t gsrc = (size_t)kt * 64 + schunk * 8;
            uint4 va = *(const uint4*)(fnb + (size_t)(i0 + row) * DIM + gsrc);
            uint4 vb = *(const uint4*)(fnb + (size_t)(j0 + row) * DIM + gsrc);
            const int dst = row * 64 + ((schunk ^ (row & 7)) * 8);
            *(uint4*)(As + dst) = va;
            *(uint4*)(Bs + dst) = vb;
        }
        __syncthreads();
        #pragma unroll
        for (int kk = 0; kk < 2; ++kk) {
            bf16x8 af[4], bfr[4];
            #pragma unroll
            for (int mi = 0; mi < 4; ++mi) {
                const int row = wm * 64 + mi * 16 + (lane & 15);
                const int ch  = kk * 4 + (lane >> 4);
                af[mi] = *(const bf16x8*)(As + row * 64 + ((ch ^ (row & 7)) * 8));
            }
            #pragma unroll
            for (int ni = 0; ni < 4; ++ni) {
                const int row = wn * 64 + ni * 16 + (lane & 15);
                const int ch  = kk * 4 + (lane >> 4);
                bfr[ni] = *(const bf16x8*)(Bs + row * 64 + ((ch ^ (row & 7)) * 8));
            }
            #pragma unroll
            for (int mi = 0; mi < 4; ++mi)
                #pragma unroll
                for (int ni = 0; ni < 4; ++ni)
                    acc[mi][ni] = __builtin_amdgcn_mfma_f32_16x16x32_bf16(
                        af[mi], bfr[ni], acc[mi][ni], 0, 0, 0);
        }
        __syncthreads();
    }

    const int cq = lane >> 4;
    const int cc = lane & 15;
    #pragma unroll
    for (int mi = 0; mi < 4; ++mi) {
        #pragma unroll
        for (int ni = 0; ni < 4; ++ni) {
            const int col  = j0 + wn * 64 + ni * 16 + cc;
            const int rowb = i0 + wm * 64 + mi * 16 + cq * 4;
            #pragma unroll
            for (int v = 0; v < 4; ++v)
                S[(size_t)(rowb + v) * NROWS + col] = acc[mi][ni][v];
        }
    }
}

// suffix-scan a 256-bin histogram within one wave, pick threshold digit
__device__ __forceinline__ void radix_scan(const unsigned* hb, int lane,
                                           unsigned& P, unsigned& K, int shift) {
    const uint4 h = ((const uint4*)hb)[lane];
    const unsigned s3 = h.w;
    const unsigned s2 = h.z + s3;
    const unsigned s1 = h.y + s2;
    const unsigned s0 = h.x + s1;
    unsigned x = s0;
    #pragma unroll
    for (int d = 1; d < 64; d <<= 1) {
        const unsigned y = __shfl_down(x, d, 64);
        if (lane + d < 64) x += y;
    }
    const unsigned E = x - s0;                    // sum over lanes > lane
    unsigned pk = 0u;
    const unsigned Sv0 = E + s0, Sv1 = E + s1, Sv2 = E + s2, Sv3 = E + s3;
    if (Sv0 >= K && Sv0 - h.x < K) pk = ((unsigned)(lane*4+0) << 16) | (K - (Sv0 - h.x));
    if (Sv1 >= K && Sv1 - h.y < K) pk = ((unsigned)(lane*4+1) << 16) | (K - (Sv1 - h.y));
    if (Sv2 >= K && Sv2 - h.z < K) pk = ((unsigned)(lane*4+2) << 16) | (K - (Sv2 - h.z));
    if (Sv3 >= K && Sv3 - h.w < K) pk = ((unsigned)(lane*4+3) << 16) | (K - (Sv3 - h.w));
    #pragma unroll
    for (int m = 1; m < 64; m <<= 1) pk |= __shfl_xor(pk, m, 64);
    P |= (pk >> 16) << shift;
    K  = pk & 0xFFFFu;
}

// 4 waves per row, 16 cols/lane, quantized 24-bit radix select.
// q spreads over ~60 top-byte bins -> plain LDS atomics are ~2-way conflicts
// (free), no ballots/leader election. 3 passes, 7 barriers total.
// Selection at 24-bit granularity (dot quantum 1.2e-7): differs from exact
// fp32 topk only when boundary keys collide within 1.2e-7 (~0.2% of rows),
// loss impact <1e-5 vs threshold 2.8e-1. dot recovered as 1 - q*2^-31.
__global__ __launch_bounds__(256) void rowsel_q_kernel(
        const float* __restrict__ S,
        const unsigned char* __restrict__ lab8,
        float* __restrict__ out)
{
    __shared__ unsigned hist[2][256];
    __shared__ float    zb[4];
    __shared__ unsigned tieb[4];
    __shared__ float    sdb[4];
    __shared__ int      cntb[4];

    const int tid  = threadIdx.x;
    const int lane = tid & 63;
    const int w    = tid >> 6;
    const int row  = blockIdx.x;

    const float4*   S4 = (const float4*)(S + (size_t)row * NROWS) + w * 256;
    const unsigned* L4 = (const unsigned*)lab8 + w * 256;

    hist[0][tid] = 0u;
    hist[1][tid] = 0u;
    __syncthreads();                                   // B0: zeros visible

    // ---- load, quantized keys, Z, fused pass-0 histogram ----
    unsigned q[4][4];
    float z = 0.f;
    #pragma unroll
    for (int c = 0; c < 4; ++c) {
        const float4 v = S4[c * 64 + lane];
        const int jb = w * 1024 + c * 256 + lane * 4;
        q[c][0] = qkey(v.x);
        q[c][1] = qkey(v.y);
        q[c][2] = qkey(v.z);
        q[c][3] = qkey(v.w);
        z += (jb + 0 == row) ? 0.f : __expf(10.f * v.x);
        z += (jb + 1 == row) ? 0.f : __expf(10.f * v.y);
        z += (jb + 2 == row) ? 0.f : __expf(10.f * v.z);
        z += (jb + 3 == row) ? 0.f : __expf(10.f * v.w);
        atomicAdd(&hist[0][q[c][0] >> 24], 1u);
        atomicAdd(&hist[0][q[c][1] >> 24], 1u);
        atomicAdd(&hist[0][q[c][2] >> 24], 1u);
        atomicAdd(&hist[0][q[c][3] >> 24], 1u);
    }
    #pragma unroll
    for (int m = 1; m < 64; m <<= 1) z += __shfl_xor(z, m, 64);
    if (lane == 0) zb[w] = z;
    __syncthreads();                                   // B1: pass0 atomics done

    unsigned P = 0u, K = 128u;
    radix_scan(hist[0], lane, P, K, 24);

    // ---- pass 1 (bits 23..16) into hist[1] (pre-zeroed) ----
    #pragma unroll
    for (int c = 0; c < 4; ++c)
        #pragma unroll
        for (int e = 0; e < 4; ++e)
            if (((q[c][e] ^ P) >> 24) == 0u)
                atomicAdd(&hist[1][(q[c][e] >> 16) & 255u], 1u);
    __syncthreads();                                   // B2
    radix_scan(hist[1], lane, P, K, 16);
    hist[0][tid] = 0u;                                 // re-zero for pass 2
    __syncthreads();                                   // B3

    // ---- pass 2 (bits 15..8) into hist[0] ----
    #pragma unroll
    for (int c = 0; c < 4; ++c)
        #pragma unroll
        for (int e = 0; e < 4; ++e)
            if (((q[c][e] ^ P) >> 16) == 0u)
                atomicAdd(&hist[0][(q[c][e] >> 8) & 255u], 1u);
    __syncthreads();                                   // B4
    radix_scan(hist[0], lane, P, K, 8);
    const unsigned Ph = P >> 8;                        // 24-bit threshold

    // ---- tie ranks (lane-major order within the block) ----
    int tcnt = 0;
    #pragma unroll
    for (int c = 0; c < 4; ++c)
        #pragma unroll
        for (int e = 0; e < 4; ++e) tcnt += ((q[c][e] >> 8) == Ph) ? 1 : 0;
    int p = tcnt;
    #pragma unroll
    for (int d = 1; d < 64; d <<= 1) {
        const int o = __shfl_up(p, d, 64);
        if (lane >= d) p += o;
    }
    if (lane == 63) tieb[w] = (unsigned)p;
    __syncthreads();                                   // B5
    int t = p - tcnt;
    #pragma unroll
    for (int ww = 0; ww < 4; ++ww) if (ww < w) t += (int)tieb[ww];

    // ---- accumulate over selected & same-class & j != row ----
    const unsigned my = lab8[row];
    float sd = 0.f; int cnt = 0;
    #pragma unroll
    for (int c = 0; c < 4; ++c) {
        const unsigned lw = L4[c * 64 + lane];
        const int jb = w * 1024 + c * 256 + lane * 4;
        #pragma unroll
        for (int e = 0; e < 4; ++e) {
            const unsigned qh = q[c][e] >> 8;
            bool sel = (qh > Ph);
            if (qh == Ph) { sel = (t < (int)K); ++t; }
            if (sel && (jb + e != row) && (((lw >> (8 * e)) & 255u) == my)) {
                ++cnt;
                sd += fmaf((float)q[c][e], -4.6566128730773926e-10f, 1.0f);
            }
        }
    }
    #pragma unroll
    for (int m = 1; m < 64; m <<= 1) {
        sd  += __shfl_xor(sd, m, 64);
        cnt += __shfl_xor(cnt, m, 64);
    }
    if (lane == 0) { sdb[w] = sd; cntb[w] = cnt; }
    __syncthreads();                                   // B6

    if (tid == 0) {
        const int c = cntb[0] + cntb[1] + cntb[2] + cntb[3];
        if (c > 0) {
            const float s = sdb[0] + sdb[1] + sdb[2] + sdb[3];
            const float Z = zb[0] + zb[1] + zb[2] + zb[3];
            const float mlpp = (10.f * s) / (float)c - __logf(Z);
            atomicAdd(out, -(0.1f / 0.07f) * mlpp * (1.f / (float)NROWS));
        }
    }
}

// ===========================================================================
// FALLBACK PATH (small d_ws): R2 fused kernels (verified correct)
// ===========================================================================

__global__ void prep_kernel(const float* __restrict__ feat,
                            const int* __restrict__ labels,
                            float* __restrict__ fn,
                            float* __restrict__ sq,
                            unsigned char* __restrict__ lab8,
                            float* __restrict__ out)
{
    const int row  = blockIdx.x * 4 + (threadIdx.x >> 6);
    const int lane = threadIdx.x & 63;
    float4 x = ((const float4*)feat)[(size_t)row * 64 + lane];
    float ss = x.x*x.x + x.y*x.y + x.z*x.z + x.w*x.w;
    #pragma unroll
    for (int m = 1; m < 64; m <<= 1) ss += __shfl_xor(ss, m, 64);
    const float nrm = sqrtf(ss);
    float4 f; f.x = x.x/nrm; f.y = x.y/nrm; f.z = x.z/nrm; f.w = x.w/nrm;
    ((float4*)fn)[(size_t)row * 64 + lane] = f;
    float s2 = f.x*f.x + f.y*f.y + f.z*f.z + f.w*f.w;
    #pragma unroll
    for (int m = 1; m < 64; m <<= 1) s2 += __shfl_xor(s2, m, 64);
    if (lane == 0) {
        sq[row]  = s2;
        lab8[row] = (unsigned char)labels[row & HALF_MASK];
    }
    if (blockIdx.x == 0 && threadIdx.x == 0) out[0] = 0.0f;
}

#define R 4
__global__ __launch_bounds__(BLOCK, 3) void rowloss_kernel(
        const float* __restrict__ fn,
        const float* __restrict__ sq,
        const unsigned char* __restrict__ lab8,
        float* __restrict__ out)
{
    __shared__ __align__(16) float fi[R][DIM];
    __shared__ unsigned hist[R * 256];
    __shared__ float    wz[R][4];
    __shared__ unsigned wsc[R][4];
    __shared__ unsigned selT[R], selK[R];
    __shared__ float    wsd[R][4];
    __shared__ int      wcnt[R][4];

    const int tid  = threadIdx.x;
    const int lane = tid & 63;
    const int wv   = tid >> 6;
    const int i0   = blockIdx.x * R;
    const int j0   = tid * 16;

    for (int idx = tid; idx < R * DIM; idx += BLOCK)
        fi[idx >> 8][idx & 255] = fn[(size_t)i0 * DIM + idx];
    __syncthreads();

    const float4* fn4 = (const float4*)fn;
    const float4* fi4 = (const float4*)&fi[0][0];

    float acc[16][R];
    #pragma unroll
    for (int jj = 0; jj < 16; ++jj)
        #pragma unroll
        for (int r = 0; r < R; ++r) acc[jj][r] = 0.0f;

    for (int c = 0; c < 32; ++c) {
        float fir[R][8];
        #pragma unroll
        for (int r = 0; r < R; ++r) {
            float4 a = fi4[r * 64 + c * 2];
            float4 b = fi4[r * 64 + c * 2 + 1];
            fir[r][0] = a.x; fir[r][1] = a.y; fir[r][2] = a.z; fir[r][3] = a.w;
            fir[r][4] = b.x; fir[r][5] = b.y; fir[r][6] = b.z; fir[r][7] = b.w;
        }
        #pragma unroll
        for (int jj = 0; jj < 16; ++jj) {
            const float4* pp = fn4 + (size_t)(j0 + jj) * 64 + c * 2;
            float4 x = pp[0];
            float4 y = pp[1];
            #pragma unroll
            for (int r = 0; r < R; ++r) {
                float s = acc[jj][r];
                s = fmaf(x.x, fir[r][0], s); s = fmaf(x.y, fir[r][1], s);
                s = fmaf(x.z, fir[r][2], s); s = fmaf(x.w, fir[r][3], s);
                s = fmaf(y.x, fir[r][4], s); s = fmaf(y.y, fir[r][5], s);
                s = fmaf(y.z, fir[r][6], s); s = fmaf(y.w, fir[r][7], s);
                acc[jj][r] = s;
            }
        }
    }

    float sqr[16];
    #pragma unroll
    for (int k = 0; k < 16; ++k) sqr[k] = sq[j0 + k];

    float lzr[R];
    {
        float zloc[R];
        #pragma unroll
        for (int r = 0; r < R; ++r) {
            const int ir = i0 + r;
            float z = 0.0f;
            #pragma unroll
            for (int k = 0; k < 16; ++k) {
                float e = __expf(10.0f * acc[k][r]);
                z += (j0 + k == ir) ? 0.0f : e;
            }
            zloc[r] = z;
        }
        #pragma unroll
        for (int r = 0; r < R; ++r) {
            float z = zloc[r];
            #pragma unroll
            for (int m = 1; m < 64; m <<= 1) z += __shfl_xor(z, m, 64);
            if (lane == 0) wz[r][wv] = z;
        }
        __syncthreads();
        #pragma unroll
        for (int r = 0; r < R; ++r)
            lzr[r] = __logf(wz[r][0] + wz[r][1] + wz[r][2] + wz[r][3]);
    }

    unsigned Pr[R] = {0, 0, 0, 0};
    unsigned Kr[R] = {128u, 128u, 128u, 128u};
    #pragma unroll
    for (int pass = 0; pass < 4; ++pass) {
        const int shift = 24 - 8 * pass;
        #pragma unroll
        for (int r = 0; r < R; ++r) hist[r * 256 + tid] = 0u;
        __syncthreads();
        #pragma unroll
        for (int r = 0; r < R; ++r) {
            #pragma unroll
            for (int k = 0; k < 16; ++k) {
                unsigned uu = fkey(fmaf(-2.0f, acc[k][r], sqr[k]));
                bool act = (pass == 0) ||
                    (((unsigned long long)(uu ^ Pr[r]) >> (shift + 8)) == 0ull);
                if (act) atomicAdd(&hist[r * 256 + ((uu >> shift) & 255u)], 1u);
            }
        }
        __syncthreads();
        unsigned g[R], Pv[R];
        #pragma unroll
        for (int r = 0; r < R; ++r) { g[r] = hist[r * 256 + (255 - tid)]; Pv[r] = g[r]; }
        #pragma unroll
        for (int dd = 1; dd < 64; dd <<= 1) {
            #pragma unroll
            for (int r = 0; r < R; ++r) {
                unsigned o = __shfl_up(Pv[r], dd, 64);
                if (lane >= dd) Pv[r] += o;
            }
        }
        if (lane == 63) {
            #pragma unroll
            for (int r = 0; r < R; ++r) wsc[r][wv] = Pv[r];
        }
        __syncthreads();
        #pragma unroll
        for (int r = 0; r < R; ++r) {
            unsigned off = 0;
            #pragma unroll
            for (int ww = 0; ww < 4; ++ww) if (ww < wv) off += wsc[r][ww];
            const unsigned Sv = Pv[r] + off;
            const unsigned Sn = Sv - g[r];
            if (Sv >= Kr[r] && Sn < Kr[r]) {
                selT[r] = Pr[r] | ((unsigned)(255 - tid) << shift);
                selK[r] = Kr[r] - Sn;
            }
        }
        __syncthreads();
        #pragma unroll
        for (int r = 0; r < R; ++r) { Pr[r] = selT[r]; Kr[r] = selK[r]; }
        __syncthreads();
    }

    int tb[R];
    {
        int tcr[R], Pt[R];
        #pragma unroll
        for (int r = 0; r < R; ++r) {
            int c = 0;
            #pragma unroll
            for (int k = 0; k < 16; ++k)
                if (fkey(fmaf(-2.0f, acc[k][r], sqr[k])) == Pr[r]) c++;
            tcr[r] = c; Pt[r] = c;
        }
        #pragma unroll
        for (int dd = 1; dd < 64; dd <<= 1) {
            #pragma unroll
            for (int r = 0; r < R; ++r) {
                int o = __shfl_up(Pt[r], dd, 64);
                if (lane >= dd) Pt[r] += o;
            }
        }
        if (lane == 63) {
            #pragma unroll
            for (int r = 0; r < R; ++r) wsc[r][wv] = (unsigned)Pt[r];
        }
        __syncthreads();
        #pragma unroll
        for (int r = 0; r < R; ++r) {
            int off = 0;
            #pragma unroll
            for (int ww = 0; ww < 4; ++ww) if (ww < wv) off += (int)wsc[r][ww];
            tb[r] = Pt[r] + off - tcr[r];
        }
    }

    const uint4 labv = ((const uint4*)lab8)[tid];
    const unsigned labw[4] = {labv.x, labv.y, labv.z, labv.w};

    #pragma unroll
    for (int r = 0; r < R; ++r) {
        const int ir = i0 + r;
        const unsigned my = lab8[ir];
        float sd = 0.0f; int cnt = 0; int t = tb[r];
        #pragma unroll
        for (int k = 0; k < 16; ++k) {
            const unsigned uu = fkey(fmaf(-2.0f, acc[k][r], sqr[k]));
            bool sel = (uu > Pr[r]);
            if (uu == Pr[r]) { sel = (t < (int)Kr[r]); t++; }
            const unsigned lj = (labw[k >> 2] >> ((k & 3) * 8)) & 255u;
            if (sel && (j0 + k != ir) && lj == my) { cnt++; sd += acc[k][r]; }
        }
        #pragma unroll
        for (int m = 1; m < 64; m <<= 1) {
            sd  += __shfl_xor(sd, m, 64);
            cnt += __shfl_xor(cnt, m, 64);
        }
        if (lane == 0) { wsd[r][wv] = sd; wcnt[r][wv] = cnt; }
    }
    __syncthreads();

    if (tid < R) {
        const int r = tid;
        const int c = wcnt[r][0] + wcnt[r][1] + wcnt[r][2] + wcnt[r][3];
        if (c > 0) {
            const float sd = wsd[r][0] + wsd[r][1] + wsd[r][2] + wsd[r][3];
            const float mlpp = (10.0f * sd) / (float)c - lzr[r];
            atomicAdd(out, -(0.1f / 0.07f) * mlpp * (1.0f / (float)NROWS));
        }
    }
}

// ===========================================================================

extern "C" void kernel_launch(void* const* d_in, const int* in_sizes, int n_in,
                              void* d_out, int out_size, void* d_ws, size_t ws_size,
                              hipStream_t stream) {
    (void)in_sizes; (void)n_in; (void)out_size;
    const float* feat  = (const float*)d_in[0];
    const int* labels  = (const int*)d_in[1];
    float* out = (float*)d_out;

    const size_t offS = 0;                                   // 4096*4096 f32
    const size_t offF = (size_t)NROWS * NROWS * 4;           // fn bf16
    const size_t offQ = offF + (size_t)NROWS * DIM * 2;      // sq f32
    const size_t offL = offQ + (size_t)NROWS * 4;            // labels u8
    const size_t need = offL + (size_t)NROWS;

    if (ws_size >= need) {
        float* S   = (float*)((char*)d_ws + offS);
        short* fnb = (short*)((char*)d_ws + offF);
        float* sq  = (float*)((char*)d_ws + offQ);
        unsigned char* lab8 = (unsigned char*)((char*)d_ws + offL);

        prep_bf16_kernel<<<NROWS / 4, BLOCK, 0, stream>>>(feat, labels, fnb, sq, lab8, out);
        gram_kernel<<<(NROWS / 128) * (NROWS / 128), BLOCK, 0, stream>>>(fnb, S);
        rowsel_q_kernel<<<NROWS, BLOCK, 0, stream>>>(S, lab8, out);
    } else {
        float* fn = (float*)d_ws;
        float* sq = fn + (size_t)NROWS * DIM;
        unsigned char* lab8 = (unsigned char*)(sq + NROWS);

        prep_kernel<<<NROWS / 4, BLOCK, 0, stream>>>(feat, labels, fn, sq, lab8, out);
        rowloss_kernel<<<NROWS / R, BLOCK, 0, stream>>>(fn, sq, lab8, out);
    }
}